// Round 9
// baseline (1911.000 us; speedup 1.0000x reference)
//
#include <hip/hip_runtime.h>

typedef unsigned short u16;
typedef unsigned int u32;

#define W_ 224
#define H_ 128
#define C_ 128
#define NH 8
#define HD 16
#define ROWS_ (W_ * H_)          // 28672 rows per image
#define PREP_STRIDE 4128
#define KSTR 40
#define VSTR 232

typedef __bf16 bf16x8 __attribute__((ext_vector_type(8)));
typedef float f32x4 __attribute__((ext_vector_type(4)));

__device__ __forceinline__ u16 f2bf(float f) {
  u32 u = __float_as_uint(f);
  return (u16)((u + 0x7FFFu + ((u >> 16) & 1u)) >> 16);
}
__device__ __forceinline__ float bflo(u32 u) { return __uint_as_float(u << 16); }
__device__ __forceinline__ float bfhi(u32 u) { return __uint_as_float(u & 0xFFFF0000u); }

// ---------------------------------------------------------------------------
// Rank-1 PE decomposition prep: rpe[d] = (d-223)*(W u) + b -> per-row affine.
// ---------------------------------------------------------------------------
__global__ __launch_bounds__(256) void prep_kernel(
    const float* __restrict__ self_Wi, const float* __restrict__ self_bi,
    const float* __restrict__ cross_Wi, const float* __restrict__ cross_bi,
    float* __restrict__ prep) {
  __shared__ float u[128];
  __shared__ float A[256];
  const int s = blockIdx.x, l = s >> 1;
  const float* Wi = (s & 1) ? cross_Wi + (size_t)l * 384 * 128 : self_Wi + (size_t)l * 384 * 128;
  const float* bi = (s & 1) ? cross_bi + l * 384 : self_bi + l * 384;
  const int tid = threadIdx.x;
  if (tid < 128) {
    float ex = (float)(tid & ~1) * (1.f / 128.f);
    u[tid] = expf(-ex * logf(10000.f));
  }
  __syncthreads();
  {
    float a = 0.f;
    const float* wr = Wi + (size_t)tid * 128;
    for (int f = 0; f < 128; ++f) a += wr[f] * u[f];
    A[tid] = a;
  }
  __syncthreads();
  float* out = prep + (size_t)s * PREP_STRIDE;
  for (int t = tid; t < 4096; t += 256) {
    int v = t >> 10, e = (t >> 7) & 7, f = t & 127;
    float acc = 0.f;
#pragma unroll
    for (int c = 0; c < 16; ++c) {
      int qrow = e * 16 + c, krow = 128 + e * 16 + c;
      if (v == 0)      acc += Wi[(size_t)qrow * 128 + f] * A[krow];
      else if (v == 1) acc += Wi[(size_t)qrow * 128 + f] * bi[krow];
      else if (v == 2) acc += Wi[(size_t)krow * 128 + f] * A[qrow];
      else             acc += Wi[(size_t)krow * 128 + f] * bi[qrow];
    }
    out[t] = acc * 0.25f;
  }
  if (tid < 32) {
    int v = tid >> 3, e = tid & 7;
    float acc = 0.f;
#pragma unroll
    for (int c = 0; c < 16; ++c) {
      int qrow = e * 16 + c, krow = 128 + e * 16 + c;
      if (v == 0)      acc += bi[qrow] * A[krow];
      else if (v == 1) acc += bi[qrow] * bi[krow];
      else if (v == 2) acc += bi[krow] * A[qrow];
      else             acc += bi[krow] * bi[qrow];
    }
    out[4096 + tid] = acc * 0.25f;
  }
}

// ---------------------------------------------------------------------------
// Affine-PE table kernel (R6-proven GEMV; LN recomputed in-register).
// mode 0 (self): both sides, b_out = half*128 + blow.
// mode 1 (cross): xl half -> k-side, xr half -> q-side, b_out = blow.
// ---------------------------------------------------------------------------
__global__ __launch_bounds__(256) void tab_kernel(
    const float* __restrict__ x, const float* __restrict__ g,
    const float* __restrict__ b, const float* __restrict__ wq,
    const float* __restrict__ cq, float* __restrict__ outA, float* __restrict__ outB,
    const float* __restrict__ wk, const float* __restrict__ ck,
    float* __restrict__ outG, float* __restrict__ outD, int mode) {
  __shared__ float ys[4][128];
  __shared__ float ws[32][129];
  const int tid = threadIdx.x;
  for (int t = tid; t < 2048; t += 256) ws[t >> 7][t & 127] = wq[t];
  for (int t = tid; t < 2048; t += 256) ws[16 + (t >> 7)][t & 127] = wk[t];
  const int row = blockIdx.x * 4 + (tid >> 6);
  const int lane = tid & 63;
  const float2* xp = (const float2*)(x + (size_t)row * 128);
  float2 v = xp[lane];
  float s1 = v.x + v.y, s2 = v.x * v.x + v.y * v.y;
#pragma unroll
  for (int k = 1; k < 64; k <<= 1) {
    s1 += __shfl_xor(s1, k);
    s2 += __shfl_xor(s2, k);
  }
  float mean = s1 * (1.f / 128.f);
  float var = s2 * (1.f / 128.f) - mean * mean;
  float rstd = rsqrtf(var + 1e-5f);
  float2 gg = ((const float2*)g)[lane];
  float2 bb = ((const float2*)b)[lane];
  float y0 = (v.x - mean) * rstd * gg.x + bb.x;
  float y1 = (v.y - mean) * rstd * gg.y + bb.y;
  ys[tid >> 6][2 * lane] = y0;
  ys[tid >> 6][2 * lane + 1] = y1;
  __syncthreads();
  if (tid < 128) {
    const int r = tid >> 5, o = tid & 31;
    const int side = o >> 4, oo = o & 15;
    const int p = blockIdx.x * 4 + r;
    const int half = (p >= ROWS_) ? 1 : 0;
    const int ploc = p - half * ROWS_;
    const bool active = (mode == 0) || (half ? (side == 0) : (side == 1));
    if (active) {
      const float* wrow = ws[side * 16 + oo];
      const float* yr = ys[r];
      float a0 = 0.f, a1 = 0.f, a2 = 0.f, a3 = 0.f;
#pragma unroll 4
      for (int f = 0; f < 128; f += 4) {
        a0 += yr[f] * wrow[f];
        a1 += yr[f + 1] * wrow[f + 1];
        a2 += yr[f + 2] * wrow[f + 2];
        a3 += yr[f + 3] * wrow[f + 3];
      }
      float acc = (a0 + a1) + (a2 + a3);
      int i = ploc >> 7, blow = ploc & 127;
      int b_out = (mode == 0) ? half * 128 + blow : blow;
      int val = oo >> 3, e = oo & 7;
      float c = side ? ck[val * 8 + e] : cq[val * 8 + e];
      float* dst = side ? (val ? outD : outG) : (val ? outB : outA);
      dst[((size_t)(b_out * 8 + e)) * 224 + i] = acc + c;
    }
  }
}

// ---------------------------------------------------------------------------
// Plain 64x64-tile bf16 MFMA GEMM (feat conv): fout = A*B^T + bias.
// ---------------------------------------------------------------------------
__global__ __launch_bounds__(256) void gemm_plain(
    const u16* __restrict__ A, const u16* __restrict__ B,
    const float* __restrict__ bias, float* __restrict__ fout) {
  __shared__ u16 As[64 * 136];
  __shared__ u16 Bs[64 * 136];
  const int tid = threadIdx.x;
  const int M0 = blockIdx.x * 64, N0 = blockIdx.y * 64;
  const uint4* Ag = (const uint4*)(A + (size_t)M0 * 128);
  const uint4* Bg = (const uint4*)(B + (size_t)N0 * 128);
  for (int t = tid; t < 1024; t += 256) {
    int row = t >> 4, cc = t & 15;
    *(uint4*)&As[row * 136 + cc * 8] = Ag[row * 16 + cc];
  }
  for (int t = tid; t < 1024; t += 256) {
    int row = t >> 4, cc = t & 15;
    *(uint4*)&Bs[row * 136 + cc * 8] = Bg[row * 16 + cc];
  }
  __syncthreads();
  const int wave = tid >> 6, lane = tid & 63;
  const int wm = (wave >> 1) * 32, wn = (wave & 1) * 32;
  const int lr = lane & 15, kq = (lane >> 4) * 8;
  f32x4 acc[2][2] = {};
#pragma unroll
  for (int ks = 0; ks < 4; ++ks) {
    int ko = ks * 32 + kq;
    bf16x8 a0 = *(const bf16x8*)&As[(wm + lr) * 136 + ko];
    bf16x8 a1 = *(const bf16x8*)&As[(wm + 16 + lr) * 136 + ko];
    bf16x8 b0 = *(const bf16x8*)&Bs[(wn + lr) * 136 + ko];
    bf16x8 b1 = *(const bf16x8*)&Bs[(wn + 16 + lr) * 136 + ko];
    acc[0][0] = __builtin_amdgcn_mfma_f32_16x16x32_bf16(a0, b0, acc[0][0], 0, 0, 0);
    acc[0][1] = __builtin_amdgcn_mfma_f32_16x16x32_bf16(a0, b1, acc[0][1], 0, 0, 0);
    acc[1][0] = __builtin_amdgcn_mfma_f32_16x16x32_bf16(a1, b0, acc[1][0], 0, 0, 0);
    acc[1][1] = __builtin_amdgcn_mfma_f32_16x16x32_bf16(a1, b1, acc[1][1], 0, 0, 0);
  }
  const int colq = lane & 15, rowq = (lane >> 4) * 4;
#pragma unroll
  for (int tm = 0; tm < 2; ++tm)
#pragma unroll
    for (int tn = 0; tn < 2; ++tn) {
#pragma unroll
      for (int r = 0; r < 4; ++r) {
        int row = M0 + wm + tm * 16 + rowq + r;
        int col = N0 + wn + tn * 16 + colq;
        fout[(size_t)row * 128 + col] = acc[tm][tn][r] + bias[col];
      }
    }
}

// ---------------------------------------------------------------------------
// Self QKV GEMM with in-register LN of the fp32 A-tile (no write-back).
// Grid (896, 6); rows cover xl+xr (row >= ROWS_ -> b += 128).
// ---------------------------------------------------------------------------
__global__ __launch_bounds__(256) void gemm_qkv_self(
    const float* __restrict__ X, const u16* __restrict__ Bw,
    const float* __restrict__ bias, u16* __restrict__ o0, u16* __restrict__ o1,
    u16* __restrict__ o2, const float* __restrict__ lng,
    const float* __restrict__ lnb) {
  __shared__ u16 As[64 * 136];
  __shared__ u16 Bs[64 * 136];
  const int tid = threadIdx.x;
  const int M0 = blockIdx.x * 64, N0 = blockIdx.y * 64;
  {
    const uint4* Bg = (const uint4*)(Bw + (size_t)N0 * 128);
    for (int t = tid; t < 1024; t += 256) {
      int row = t >> 4, cc = t & 15;
      *(uint4*)&Bs[row * 136 + cc * 8] = Bg[row * 16 + cc];
    }
  }
  {
    const int wv = tid >> 6, lane = tid & 63;
    float2 gg = ((const float2*)lng)[lane];
    float2 bb = ((const float2*)lnb)[lane];
    for (int t = 0; t < 16; ++t) {
      const int r = wv * 16 + t;
      float2 v = *(const float2*)&X[(size_t)(M0 + r) * 128 + lane * 2];
      float s1 = v.x + v.y, s2 = v.x * v.x + v.y * v.y;
#pragma unroll
      for (int k = 1; k < 64; k <<= 1) {
        s1 += __shfl_xor(s1, k);
        s2 += __shfl_xor(s2, k);
      }
      float mean = s1 * (1.f / 128.f);
      float var = s2 * (1.f / 128.f) - mean * mean;
      float rstd = rsqrtf(var + 1e-5f);
      float y0 = (v.x - mean) * rstd * gg.x + bb.x;
      float y1 = (v.y - mean) * rstd * gg.y + bb.y;
      ((u32*)As)[r * 68 + lane] = (u32)f2bf(y0) | ((u32)f2bf(y1) << 16);
    }
  }
  __syncthreads();
  const int wave = tid >> 6, lane = tid & 63;
  const int wm = (wave >> 1) * 32, wn = (wave & 1) * 32;
  const int lr = lane & 15, kq = (lane >> 4) * 8;
  f32x4 acc[2][2] = {};
#pragma unroll
  for (int ks = 0; ks < 4; ++ks) {
    int ko = ks * 32 + kq;
    bf16x8 a0 = *(const bf16x8*)&As[(wm + lr) * 136 + ko];
    bf16x8 a1 = *(const bf16x8*)&As[(wm + 16 + lr) * 136 + ko];
    bf16x8 b0 = *(const bf16x8*)&Bs[(wn + lr) * 136 + ko];
    bf16x8 b1 = *(const bf16x8*)&Bs[(wn + 16 + lr) * 136 + ko];
    acc[0][0] = __builtin_amdgcn_mfma_f32_16x16x32_bf16(a0, b0, acc[0][0], 0, 0, 0);
    acc[0][1] = __builtin_amdgcn_mfma_f32_16x16x32_bf16(a0, b1, acc[0][1], 0, 0, 0);
    acc[1][0] = __builtin_amdgcn_mfma_f32_16x16x32_bf16(a1, b0, acc[1][0], 0, 0, 0);
    acc[1][1] = __builtin_amdgcn_mfma_f32_16x16x32_bf16(a1, b1, acc[1][1], 0, 0, 0);
  }
  const int colq = lane & 15, rowq = (lane >> 4) * 4;
#pragma unroll
  for (int tm = 0; tm < 2; ++tm)
#pragma unroll
    for (int tn = 0; tn < 2; ++tn) {
#pragma unroll
      for (int r = 0; r < 4; ++r) {
        int row = M0 + wm + tm * 16 + rowq + r;
        int col = N0 + wn + tn * 16 + colq;
        float v = acc[tm][tn][r] + bias[col];
        int part = col >> 7;
        int cc = col & 127;
        int e = cc >> 4, c = cc & 15;
        int rloc = row, badd = 0;
        if (row >= ROWS_) { rloc = row - ROWS_; badd = 128; }
        int b = (rloc & 127) + badd, pos = rloc >> 7;
        size_t off = ((size_t)(b * NH + e) * W_ + pos) * HD + c;
        if (part == 0)      o0[off] = f2bf(v * 0.25f);
        else if (part == 1) o1[off] = f2bf(v);
        else                o2[off] = f2bf(v);
      }
    }
}

// ---------------------------------------------------------------------------
// Cross QKV GEMM, merged q+kv in one launch. Grid (448, 6):
// y<2: A = Xr (LN), B = cWi q-rows, q scatter (*0.25).
// y>=2: A = Xl (LN), B = cWi+128*128, k/v scatter.
// ---------------------------------------------------------------------------
__global__ __launch_bounds__(256) void gemm_qkv_cross(
    const float* __restrict__ Xl, const float* __restrict__ Xr,
    const u16* __restrict__ cWi, const float* __restrict__ cbi,
    u16* __restrict__ QB, u16* __restrict__ KB, u16* __restrict__ VB,
    const float* __restrict__ lng, const float* __restrict__ lnb) {
  __shared__ u16 As[64 * 136];
  __shared__ u16 Bs[64 * 136];
  const int tid = threadIdx.x;
  const int M0 = blockIdx.x * 64;
  const int y = blockIdx.y;
  const bool isq = (y < 2);
  const float* X = isq ? Xr : Xl;
  const u16* Bw = isq ? cWi : cWi + 128 * 128;
  const float* bias = isq ? cbi : cbi + 128;
  const int N0 = (isq ? y : y - 2) * 64;
  {
    const uint4* Bg = (const uint4*)(Bw + (size_t)N0 * 128);
    for (int t = tid; t < 1024; t += 256) {
      int row = t >> 4, cc = t & 15;
      *(uint4*)&Bs[row * 136 + cc * 8] = Bg[row * 16 + cc];
    }
  }
  {
    const int wv = tid >> 6, lane = tid & 63;
    float2 gg = ((const float2*)lng)[lane];
    float2 bb = ((const float2*)lnb)[lane];
    for (int t = 0; t < 16; ++t) {
      const int r = wv * 16 + t;
      float2 v = *(const float2*)&X[(size_t)(M0 + r) * 128 + lane * 2];
      float s1 = v.x + v.y, s2 = v.x * v.x + v.y * v.y;
#pragma unroll
      for (int k = 1; k < 64; k <<= 1) {
        s1 += __shfl_xor(s1, k);
        s2 += __shfl_xor(s2, k);
      }
      float mean = s1 * (1.f / 128.f);
      float var = s2 * (1.f / 128.f) - mean * mean;
      float rstd = rsqrtf(var + 1e-5f);
      float y0 = (v.x - mean) * rstd * gg.x + bb.x;
      float y1 = (v.y - mean) * rstd * gg.y + bb.y;
      ((u32*)As)[r * 68 + lane] = (u32)f2bf(y0) | ((u32)f2bf(y1) << 16);
    }
  }
  __syncthreads();
  const int wave = tid >> 6, lane = tid & 63;
  const int wm = (wave >> 1) * 32, wn = (wave & 1) * 32;
  const int lr = lane & 15, kq = (lane >> 4) * 8;
  f32x4 acc[2][2] = {};
#pragma unroll
  for (int ks = 0; ks < 4; ++ks) {
    int ko = ks * 32 + kq;
    bf16x8 a0 = *(const bf16x8*)&As[(wm + lr) * 136 + ko];
    bf16x8 a1 = *(const bf16x8*)&As[(wm + 16 + lr) * 136 + ko];
    bf16x8 b0 = *(const bf16x8*)&Bs[(wn + lr) * 136 + ko];
    bf16x8 b1 = *(const bf16x8*)&Bs[(wn + 16 + lr) * 136 + ko];
    acc[0][0] = __builtin_amdgcn_mfma_f32_16x16x32_bf16(a0, b0, acc[0][0], 0, 0, 0);
    acc[0][1] = __builtin_amdgcn_mfma_f32_16x16x32_bf16(a0, b1, acc[0][1], 0, 0, 0);
    acc[1][0] = __builtin_amdgcn_mfma_f32_16x16x32_bf16(a1, b0, acc[1][0], 0, 0, 0);
    acc[1][1] = __builtin_amdgcn_mfma_f32_16x16x32_bf16(a1, b1, acc[1][1], 0, 0, 0);
  }
  const int colq = lane & 15, rowq = (lane >> 4) * 4;
#pragma unroll
  for (int tm = 0; tm < 2; ++tm)
#pragma unroll
    for (int tn = 0; tn < 2; ++tn) {
#pragma unroll
      for (int r = 0; r < 4; ++r) {
        int row = M0 + wm + tm * 16 + rowq + r;
        int col = N0 + wn + tn * 16 + colq;
        float v = acc[tm][tn][r] + bias[col];
        int cc = col & 127;
        int e = cc >> 4, c = cc & 15;
        int b = row & 127, pos = row >> 7;
        size_t off = ((size_t)(b * NH + e) * W_ + pos) * HD + c;
        if (isq)                 QB[off] = f2bf(v * 0.25f);
        else if ((col >> 7) == 0) KB[off] = f2bf(v);
        else                      VB[off] = f2bf(v);
      }
    }
}

// ---------------------------------------------------------------------------
// Residual out-projection: X = LN(X_old) + OB@Wo^T + bias, in-place.
// One block owns ALL 128 cols of its 64-row tile (no cross-block hazard).
// Tiles >= proj_tiles do X = LN(X_old) only (cross: xr half).
// ---------------------------------------------------------------------------
__global__ __launch_bounds__(256) void gemm_res(
    const u16* __restrict__ OBp, const u16* __restrict__ Wo,
    const float* __restrict__ bias, float* __restrict__ X, int proj_tiles,
    const float* __restrict__ lng, const float* __restrict__ lnb) {
  __shared__ __align__(16) char smem[52224];
  u16* As = (u16*)smem;                 // 64*136 bf16
  u16* Bs = (u16*)(smem + 17408);       // 128*136 bf16
  float* Af = (float*)smem;             // 64*132 fp32, reused after MFMA
  const int tid = threadIdx.x;
  const int M0 = blockIdx.x * 64;
  const bool proj = ((int)blockIdx.x < proj_tiles);
  const int wave = tid >> 6, lane = tid & 63;

  if (proj) {
    const uint4* Ag = (const uint4*)(OBp + (size_t)M0 * 128);
    for (int t = tid; t < 1024; t += 256) {
      int row = t >> 4, cc = t & 15;
      *(uint4*)&As[row * 136 + cc * 8] = Ag[row * 16 + cc];
    }
    const uint4* Bg = (const uint4*)Wo;
    for (int t = tid; t < 2048; t += 256) {
      int row = t >> 4, cc = t & 15;
      *(uint4*)&Bs[row * 136 + cc * 8] = Bg[row * 16 + cc];
    }
  }
  __syncthreads();
  f32x4 acc[2][4] = {};
  if (proj) {
    const int wm = (wave >> 1) * 32, wn = (wave & 1) * 64;
    const int lr = lane & 15, kq = (lane >> 4) * 8;
#pragma unroll
    for (int ks = 0; ks < 4; ++ks) {
      int ko = ks * 32 + kq;
      bf16x8 a0 = *(const bf16x8*)&As[(wm + lr) * 136 + ko];
      bf16x8 a1 = *(const bf16x8*)&As[(wm + 16 + lr) * 136 + ko];
#pragma unroll
      for (int tn = 0; tn < 4; ++tn) {
        bf16x8 b0 = *(const bf16x8*)&Bs[(wn + tn * 16 + lr) * 136 + ko];
        acc[0][tn] = __builtin_amdgcn_mfma_f32_16x16x32_bf16(a0, b0, acc[0][tn], 0, 0, 0);
        acc[1][tn] = __builtin_amdgcn_mfma_f32_16x16x32_bf16(a1, b0, acc[1][tn], 0, 0, 0);
      }
    }
  }
  __syncthreads();  // MFMA reads of As/Bs done; Af may overwrite
  // LN of X_old tile
  {
    float2 gg = ((const float2*)lng)[lane];
    float2 bb = ((const float2*)lnb)[lane];
    for (int t = 0; t < 16; ++t) {
      const int r = wave * 16 + t;
      float2 v = *(const float2*)&X[(size_t)(M0 + r) * 128 + lane * 2];
      float s1 = v.x + v.y, s2 = v.x * v.x + v.y * v.y;
#pragma unroll
      for (int k = 1; k < 64; k <<= 1) {
        s1 += __shfl_xor(s1, k);
        s2 += __shfl_xor(s2, k);
      }
      float mean = s1 * (1.f / 128.f);
      float var = s2 * (1.f / 128.f) - mean * mean;
      float rstd = rsqrtf(var + 1e-5f);
      float y0 = (v.x - mean) * rstd * gg.x + bb.x;
      float y1 = (v.y - mean) * rstd * gg.y + bb.y;
      if (proj) {
        Af[r * 132 + lane * 2] = y0;
        Af[r * 132 + lane * 2 + 1] = y1;
      } else {
        *(float2*)&X[(size_t)(M0 + r) * 128 + lane * 2] = make_float2(y0, y1);
      }
    }
  }
  if (proj) {
    __syncthreads();
    const int wm = (wave >> 1) * 32, wn = (wave & 1) * 64;
    const int colq = lane & 15, rowq = (lane >> 4) * 4;
#pragma unroll
    for (int tm = 0; tm < 2; ++tm)
#pragma unroll
      for (int tn = 0; tn < 4; ++tn)
#pragma unroll
        for (int r = 0; r < 4; ++r) {
          int rl = wm + tm * 16 + rowq + r;
          int col = wn + tn * 16 + colq;
          X[(size_t)(M0 + rl) * 128 + col] = Af[rl * 132 + col] + (acc[tm][tn][r] + bias[col]);
        }
  }
}

// ---------------------------------------------------------------------------
// MFMA flash attention per (head e, batch-row b). Two-pass softmax
// (register-resident S^T strip, exact max). PE affine term rides in 6
// zero-padded contraction slots.
// ---------------------------------------------------------------------------
__global__ __launch_bounds__(448) void attn_kernel(
    const u16* __restrict__ qb, const u16* __restrict__ kb,
    const u16* __restrict__ vb, const float* __restrict__ ALPHA,
    const float* __restrict__ BETA, const float* __restrict__ GAMMA,
    const float* __restrict__ DELTA, u16* __restrict__ obuf) {
  __shared__ u16 Ksh[224 * KSTR];
  __shared__ u16 Qsh[224 * KSTR];
  __shared__ u16 Vt[16 * VSTR];
  __shared__ u16 Pbuf[7][16 * KSTR];
  const int e = blockIdx.x, b = blockIdx.y;
  const size_t hb = (size_t)(b * NH + e);
  const int tid = threadIdx.x;
  const u32 ONE = 0x3F80u;

  if (tid < 224) {
    const int j = tid;
    const uint4* src = (const uint4*)(kb + (hb * W_ + j) * HD);
    uint4 a = src[0], b2 = src[1];
    *(uint4*)&Ksh[j * KSTR] = a;
    *(uint4*)&Ksh[j * KSTR + 8] = b2;
    float G = GAMMA[hb * 224 + j];
    float D = DELTA[hb * 224 + j];
    float jf = (float)j;
    float P = G * jf + D;
    u16 Phi = f2bf(P);
    float Plo = P - __uint_as_float((u32)Phi << 16);
    u32* ex = (u32*)&Ksh[j * KSTR + 16];
    ex[0] = (u32)f2bf(G) | ((u32)Phi << 16);
    ex[1] = (u32)f2bf(Plo) | ((u32)f2bf(jf) << 16);
    ex[2] = ONE | (ONE << 16);
#pragma unroll
    for (int z = 3; z < 12; ++z) ex[z] = 0;
    const uint4* vsrc = (const uint4*)(vb + (hb * W_ + j) * HD);
    uint4 va = vsrc[0], vb4 = vsrc[1];
    u32 w[8] = {va.x, va.y, va.z, va.w, vb4.x, vb4.y, vb4.z, vb4.w};
#pragma unroll
    for (int c = 0; c < 16; ++c)
      Vt[c * VSTR + j] = (c & 1) ? (u16)(w[c >> 1] >> 16) : (u16)(w[c >> 1] & 0xFFFF);
  } else {
    const int i = tid - 224;
    const uint4* src = (const uint4*)(qb + (hb * W_ + i) * HD);
    uint4 a = src[0], b2 = src[1];
    *(uint4*)&Qsh[i * KSTR] = a;
    *(uint4*)&Qsh[i * KSTR + 8] = b2;
    float al = ALPHA[hb * 224 + i];
    float be = BETA[hb * 224 + i];
    float ifl = (float)i;
    float Q = be - al * ifl;
    u16 Qhi = f2bf(Q);
    float Qlo = Q - __uint_as_float((u32)Qhi << 16);
    u32* ex = (u32*)&Qsh[i * KSTR + 16];
    ex[0] = (u32)f2bf(-ifl) | (ONE << 16);
    ex[1] = ONE | ((u32)f2bf(al) << 16);
    ex[2] = (u32)Qhi | ((u32)f2bf(Qlo) << 16);
#pragma unroll
    for (int z = 3; z < 12; ++z) ex[z] = 0;
  }
  __syncthreads();

  const int wid = tid >> 6, lane = tid & 63;
  const int g = lane >> 4, li = lane & 15;
  u16* pb = &Pbuf[wid][0];
  const int obase = (b & 128) ? ROWS_ : 0;
  const int blow = b & 127;

  for (int qt = wid * 2; qt < wid * 2 + 2; ++qt) {
    const int i0 = qt * 16;
    const bf16x8 Bq = *(const bf16x8*)&Qsh[(i0 + li) * KSTR + g * 8];
    f32x4 C[7][2];
#pragma unroll
    for (int js = 0; js < 7; ++js) {
      const bf16x8 A0 = *(const bf16x8*)&Ksh[(js * 32 + li) * KSTR + g * 8];
      const bf16x8 A1 = *(const bf16x8*)&Ksh[(js * 32 + 16 + li) * KSTR + g * 8];
      const f32x4 Z = {0.f, 0.f, 0.f, 0.f};
      C[js][0] = __builtin_amdgcn_mfma_f32_16x16x32_bf16(A0, Bq, Z, 0, 0, 0);
      C[js][1] = __builtin_amdgcn_mfma_f32_16x16x32_bf16(A1, Bq, Z, 0, 0, 0);
    }
    float m = -1e30f;
#pragma unroll
    for (int js = 0; js < 7; ++js)
#pragma unroll
      for (int h = 0; h < 2; ++h)
        m = fmaxf(m, fmaxf(fmaxf(C[js][h][0], C[js][h][1]), fmaxf(C[js][h][2], C[js][h][3])));
    m = fmaxf(m, __shfl_xor(m, 16));
    m = fmaxf(m, __shfl_xor(m, 32));
    f32x4 O = {0.f, 0.f, 0.f, 0.f};
    float lsum = 0.f;
#pragma unroll
    for (int js = 0; js < 7; ++js) {
      float p0 = __expf(C[js][0][0] - m), p1 = __expf(C[js][0][1] - m);
      float p2 = __expf(C[js][0][2] - m), p3 = __expf(C[js][0][3] - m);
      float p4 = __expf(C[js][1][0] - m), p5 = __expf(C[js][1][1] - m);
      float p6 = __expf(C[js][1][2] - m), p7 = __expf(C[js][1][3] - m);
      lsum += ((p0 + p1) + (p2 + p3)) + ((p4 + p5) + (p6 + p7));
      u16* pr = pb + li * KSTR + g * 4;
      pr[0] = f2bf(p0); pr[1] = f2bf(p1); pr[2] = f2bf(p2); pr[3] = f2bf(p3);
      pr[16] = f2bf(p4); pr[17] = f2bf(p5); pr[18] = f2bf(p6); pr[19] = f2bf(p7);
      const bf16x8 Ap = *(const bf16x8*)&Pbuf[wid][li * KSTR + g * 8];
      const bf16x8 Bv = *(const bf16x8*)&Vt[li * VSTR + js * 32 + g * 8];
      O = __builtin_amdgcn_mfma_f32_16x16x32_bf16(Ap, Bv, O, 0, 0, 0);
    }
    lsum += __shfl_xor(lsum, 16);
    lsum += __shfl_xor(lsum, 32);
#pragma unroll
    for (int r = 0; r < 4; ++r) {
      const float lr = __shfl(lsum, g * 4 + r);
      const int irow = i0 + g * 4 + r;
      obuf[((size_t)(obase + irow * 128 + blow)) * C_ + e * HD + li] = f2bf(O[r] * (1.f / lr));
    }
  }
}

// Gather x_l/x_r[b][c][h][w] -> bf16 rows p = img*28672 + w*128 + h*2 + b.
__global__ __launch_bounds__(256) void transpose_kernel(const float* __restrict__ x_l,
                                                        const float* __restrict__ x_r,
                                                        u16* __restrict__ xT) {
  __shared__ float tile[128][57];
  const int wt = blockIdx.x * 56, hi = blockIdx.y;
  const int img = blockIdx.z >> 1, bi = blockIdx.z & 1;
  const float* x = img ? x_r : x_l;
  const int wave = threadIdx.x >> 6, lane = threadIdx.x & 63;
  for (int c = wave; c < 128; c += 4) {
    if (lane < 56)
      tile[c][lane] = x[(((size_t)bi * 128 + c) * 64 + hi) * 224 + wt + lane];
  }
  __syncthreads();
  u32* dst = (u32*)xT;
  for (int w = wave; w < 56; w += 4) {
    int p = img * ROWS_ + (wt + w) * 128 + hi * 2 + bi;
    float a = tile[lane * 2][w], b2 = tile[lane * 2 + 1][w];
    dst[(size_t)p * 64 + lane] = (u32)f2bf(a) | ((u32)f2bf(b2) << 16);
  }
}

// ---------------------------------------------------------------------------
// Final soft-argmax over recomputed layer-5 cross logits.
// ---------------------------------------------------------------------------
__global__ __launch_bounds__(448) void corresp_kernel(
    const u16* __restrict__ qb, const u16* __restrict__ kb,
    const float* __restrict__ ALPHA, const float* __restrict__ BETA,
    const float* __restrict__ GAMMA, const float* __restrict__ DELTA,
    float* __restrict__ out) {
  __shared__ __align__(16) u32 Ks[224 * 68];
  __shared__ float Gs[224], Ds[224];
  const int b = blockIdx.x, tid = threadIdx.x;
  const u32* kg = (const u32*)kb;
  for (int t = tid; t < 224 * 64; t += 448) {
    int row = t >> 6, col = t & 63;
    Ks[row * 68 + col] = kg[((size_t)(b * 8 + (col >> 3)) * 224 + row) * 8 + (col & 7)];
  }
  if (tid < 224) {
    float gs = 0.f, ds = 0.f;
#pragma unroll
    for (int e = 0; e < 8; ++e) {
      gs += GAMMA[((size_t)(b * 8 + e)) * 224 + tid];
      ds += DELTA[((size_t)(b * 8 + e)) * 224 + tid];
    }
    Gs[tid] = gs;
    Ds[tid] = ds;
  }
  __syncthreads();
  const int ii = tid >> 2, jq = tid & 3;
  const int i = blockIdx.y * 112 + ii;
  float qf[128];
  const u32* qg = (const u32*)qb;
#pragma unroll
  for (int uu = 0; uu < 64; ++uu) {
    u32 qv = qg[((size_t)(b * 8 + (uu >> 3)) * 224 + i) * 8 + (uu & 7)];
    qf[2 * uu] = bflo(qv);
    qf[2 * uu + 1] = bfhi(qv);
  }
  float ai = 0.f, bi_ = 0.f;
#pragma unroll
  for (int e = 0; e < 8; ++e) {
    ai += ALPHA[((size_t)(b * 8 + e)) * 224 + i];
    bi_ += BETA[((size_t)(b * 8 + e)) * 224 + i];
  }
  float m = -1e30f, l = 0.f, wj = 0.f;
  for (int jj = 0; jj < 56; ++jj) {
    int jo = jj + jq * 14;
    if (jo >= 56) jo -= 56;
    const int j = jq * 56 + jo;
    const u32* kr = &Ks[j * 68];
    float p0 = 0.f, p1 = 0.f, p2 = 0.f, p3 = 0.f;
#pragma unroll
    for (int w = 0; w < 16; ++w) {
      uint4 kk = *(const uint4*)&kr[w * 4];
      p0 += qf[w * 8 + 0] * bflo(kk.x) + qf[w * 8 + 1] * bfhi(kk.x);
      p1 += qf[w * 8 + 2] * bflo(kk.y) + qf[w * 8 + 3] * bfhi(kk.y);
      p2 += qf[w * 8 + 4] * bflo(kk.z) + qf[w * 8 + 5] * bfhi(kk.z);
      p3 += qf[w * 8 + 6] * bflo(kk.w) + qf[w * 8 + 7] * bfhi(kk.w);
    }
    float s = (p0 + p1) + (p2 + p3);
    s += (float)(j - i) * (ai + Gs[j]) + bi_ + Ds[j];
    if (s > m) {
      float fs = __expf(m - s);
      l *= fs;
      wj *= fs;
      m = s;
    }
    float p = __expf(s - m);
    l += p;
    wj += p * (float)j;
  }
#pragma unroll
  for (int r = 1; r <= 2; r <<= 1) {
    float mo = __shfl_xor(m, r);
    float m2 = fmaxf(m, mo);
    float fa = __expf(m - m2), fb = __expf(mo - m2);
    l = l * fa + __shfl_xor(l, r) * fb;
    wj = wj * fa + __shfl_xor(wj, r) * fb;
    m = m2;
  }
  if (jq == 0) out[(size_t)b * 224 + i] = (float)i - wj / fmaxf(l, 1e-30f);
}

// Single-launch conversion of all five weight tensors to one bf16 buffer.
#define OFF_FEAT 0
#define OFF_SWI 16384
#define OFF_SWO 311296
#define OFF_CWI 409600
#define OFF_CWO 704512
#define N_WALL 802816
__global__ __launch_bounds__(256) void cvt_all_kernel(
    const float* __restrict__ feat_w, const float* __restrict__ self_Wi,
    const float* __restrict__ self_Wo, const float* __restrict__ cross_Wi,
    const float* __restrict__ cross_Wo, u16* __restrict__ dst) {
  int idx = blockIdx.x * 256 + threadIdx.x;
  if (idx >= N_WALL) return;
  float v;
  if (idx < OFF_SWI)       v = feat_w[idx];
  else if (idx < OFF_SWO)  v = self_Wi[idx - OFF_SWI];
  else if (idx < OFF_CWI)  v = self_Wo[idx - OFF_SWO];
  else if (idx < OFF_CWO)  v = cross_Wi[idx - OFF_CWI];
  else                     v = cross_Wo[idx - OFF_CWO];
  dst[idx] = f2bf(v);
}

extern "C" void kernel_launch(void* const* d_in, const int* in_sizes, int n_in,
                              void* d_out, int out_size, void* d_ws, size_t ws_size,
                              hipStream_t stream) {
  (void)in_sizes; (void)n_in; (void)out_size; (void)ws_size;
  const float* x_l = (const float*)d_in[0];
  const float* x_r = (const float*)d_in[1];
  const float* feat_w = (const float*)d_in[2];
  const float* feat_b = (const float*)d_in[3];
  const float* self_Wi = (const float*)d_in[4];
  const float* self_bi = (const float*)d_in[5];
  const float* self_Wo = (const float*)d_in[6];
  const float* self_bo = (const float*)d_in[7];
  const float* cross_Wi = (const float*)d_in[8];
  const float* cross_bi = (const float*)d_in[9];
  const float* cross_Wo = (const float*)d_in[10];
  const float* cross_bo = (const float*)d_in[11];
  const float* ln_g = (const float*)d_in[12];
  const float* ln_b = (const float*)d_in[13];

  char* ws = (char*)d_ws;
  size_t off = 0;
  auto alloc = [&](size_t bytes) {
    char* p = ws + off;
    off += (bytes + 255) & ~(size_t)255;
    return p;
  };
  // Total ~97.2 MB — safely under the R6-proven ~112 MB footprint.
  float* XA = (float*)alloc((size_t)2 * ROWS_ * C_ * 4);   // single residual buf
  u16* QB = (u16*)alloc((size_t)256 * NH * W_ * HD * 2);   // also XT scratch
  u16* KB = (u16*)alloc((size_t)256 * NH * W_ * HD * 2);
  u16* VB = (u16*)alloc((size_t)256 * NH * W_ * HD * 2);
  u16* OB = (u16*)alloc((size_t)2 * ROWS_ * C_ * 2);
  u16* WALL = (u16*)alloc((size_t)N_WALL * 2);
  float* PREP = (float*)alloc((size_t)12 * PREP_STRIDE * 4);
  float* ALPHA = (float*)alloc((size_t)256 * NH * W_ * 4);
  float* BETA = (float*)alloc((size_t)256 * NH * W_ * 4);
  float* GAMMA = (float*)alloc((size_t)256 * NH * W_ * 4);
  float* DELTA = (float*)alloc((size_t)256 * NH * W_ * 4);

  cvt_all_kernel<<<3136, 256, 0, stream>>>(feat_w, self_Wi, self_Wo, cross_Wi, cross_Wo, WALL);
  prep_kernel<<<12, 256, 0, stream>>>(self_Wi, self_bi, cross_Wi, cross_bi, PREP);

  transpose_kernel<<<dim3(4, 64, 4), 256, 0, stream>>>(x_l, x_r, QB);
  gemm_plain<<<dim3(896, 2), 256, 0, stream>>>(QB, WALL + OFF_FEAT, feat_b, XA);

  for (int l = 0; l < 6; ++l) {
    const u16* sWi = WALL + OFF_SWI + (size_t)l * 384 * 128;
    const u16* sWo = WALL + OFF_SWO + (size_t)l * 128 * 128;
    const u16* cWi = WALL + OFF_CWI + (size_t)l * 384 * 128;
    const u16* cWo = WALL + OFF_CWO + (size_t)l * 128 * 128;
    const float* sbi = self_bi + l * 384;
    const float* sbo = self_bo + l * 128;
    const float* cbi = cross_bi + l * 384;
    const float* cbo = cross_bo + l * 128;
    const float* ps = PREP + (size_t)(l * 2) * PREP_STRIDE;
    const float* pc = PREP + (size_t)(l * 2 + 1) * PREP_STRIDE;

    // --- self attention on xl AND xr (LN fused into qkv + res gemms) ---
    tab_kernel<<<14336, 256, 0, stream>>>(XA, ln_g, ln_b, ps, ps + 4096, ALPHA, BETA,
                                          ps + 2048, ps + 4112, GAMMA, DELTA, 0);
    gemm_qkv_self<<<dim3(896, 6), 256, 0, stream>>>(XA, sWi, sbi, QB, KB, VB, ln_g, ln_b);
    attn_kernel<<<dim3(8, 256), 448, 0, stream>>>(QB, KB, VB, ALPHA, BETA, GAMMA, DELTA, OB);
    gemm_res<<<896, 256, 0, stream>>>(OB, sWo, sbo, XA, 896, ln_g, ln_b);

    // --- cross attention: q from LN(xr), k/v from LN(xl) ---
    tab_kernel<<<14336, 256, 0, stream>>>(XA, ln_g, ln_b, pc, pc + 4096, ALPHA, BETA,
                                          pc + 2048, pc + 4112, GAMMA, DELTA, 1);
    gemm_qkv_cross<<<dim3(448, 6), 256, 0, stream>>>(XA, XA + (size_t)ROWS_ * C_, cWi, cbi,
                                                     QB, KB, VB, ln_g, ln_b);
    if (l < 5) {
      attn_kernel<<<dim3(8, 128), 448, 0, stream>>>(QB, KB, VB, ALPHA, BETA, GAMMA, DELTA, OB);
      // xl: X = LN(X)+proj; xr (tiles >= 448): X = LN(X) per reference reassignment
      gemm_res<<<896, 256, 0, stream>>>(OB, cWo, cbo, XA, 448, ln_g, ln_b);
    }
    // l == 5: attention output / x updates dead; corresp reads QB/KB + tables.
  }
  corresp_kernel<<<dim3(128, 2), 448, 0, stream>>>(QB, KB, ALPHA, BETA, GAMMA, DELTA,
                                                   (float*)d_out);
}

// Round 10
// 1445.810 us; speedup vs baseline: 1.3218x; 1.3218x over previous
//
#include <hip/hip_runtime.h>

typedef unsigned short u16;
typedef unsigned int u32;

#define W_ 224
#define H_ 128
#define C_ 128
#define NH 8
#define HD 16
#define ROWS_ (W_ * H_)          // 28672 rows per image
#define PREP_STRIDE 4128
#define KSTR 40
#define VSTR 232
#define TROWS 32                 // rows per tab_kernel block

typedef __bf16 bf16x8 __attribute__((ext_vector_type(8)));
typedef float f32x4 __attribute__((ext_vector_type(4)));

__device__ __forceinline__ u16 f2bf(float f) {
  u32 u = __float_as_uint(f);
  return (u16)((u + 0x7FFFu + ((u >> 16) & 1u)) >> 16);
}
__device__ __forceinline__ float bflo(u32 u) { return __uint_as_float(u << 16); }
__device__ __forceinline__ float bfhi(u32 u) { return __uint_as_float(u & 0xFFFF0000u); }

// ---------------------------------------------------------------------------
// Rank-1 PE decomposition prep: rpe[d] = (d-223)*(W u) + b -> per-row affine.
// ---------------------------------------------------------------------------
__global__ __launch_bounds__(256) void prep_kernel(
    const float* __restrict__ self_Wi, const float* __restrict__ self_bi,
    const float* __restrict__ cross_Wi, const float* __restrict__ cross_bi,
    float* __restrict__ prep) {
  __shared__ float u[128];
  __shared__ float A[256];
  const int s = blockIdx.x, l = s >> 1;
  const float* Wi = (s & 1) ? cross_Wi + (size_t)l * 384 * 128 : self_Wi + (size_t)l * 384 * 128;
  const float* bi = (s & 1) ? cross_bi + l * 384 : self_bi + l * 384;
  const int tid = threadIdx.x;
  if (tid < 128) {
    float ex = (float)(tid & ~1) * (1.f / 128.f);
    u[tid] = expf(-ex * logf(10000.f));
  }
  __syncthreads();
  {
    float a = 0.f;
    const float* wr = Wi + (size_t)tid * 128;
    for (int f = 0; f < 128; ++f) a += wr[f] * u[f];
    A[tid] = a;
  }
  __syncthreads();
  float* out = prep + (size_t)s * PREP_STRIDE;
  for (int t = tid; t < 4096; t += 256) {
    int v = t >> 10, e = (t >> 7) & 7, f = t & 127;
    float acc = 0.f;
#pragma unroll
    for (int c = 0; c < 16; ++c) {
      int qrow = e * 16 + c, krow = 128 + e * 16 + c;
      if (v == 0)      acc += Wi[(size_t)qrow * 128 + f] * A[krow];
      else if (v == 1) acc += Wi[(size_t)qrow * 128 + f] * bi[krow];
      else if (v == 2) acc += Wi[(size_t)krow * 128 + f] * A[qrow];
      else             acc += Wi[(size_t)krow * 128 + f] * bi[qrow];
    }
    out[t] = acc * 0.25f;
  }
  if (tid < 32) {
    int v = tid >> 3, e = tid & 7;
    float acc = 0.f;
#pragma unroll
    for (int c = 0; c < 16; ++c) {
      int qrow = e * 16 + c, krow = 128 + e * 16 + c;
      if (v == 0)      acc += bi[qrow] * A[krow];
      else if (v == 1) acc += bi[qrow] * bi[krow];
      else if (v == 2) acc += bi[krow] * A[qrow];
      else             acc += bi[krow] * bi[qrow];
    }
    out[4096 + tid] = acc * 0.25f;
  }
}

// ---------------------------------------------------------------------------
// Fused LN + affine-PE tables, 32 rows per block (amortizes the 16 KB table
// staging 8x vs the R6 4-row version). Writes X = LN(X) in place (R6
// semantics) and the fp32 alpha/beta/gamma/delta tables.
// mode 0 (self): both sides, b_out = half*128 + blow.
// mode 1 (cross): xl half -> k-side, xr half -> q-side, b_out = blow.
// ---------------------------------------------------------------------------
__global__ __launch_bounds__(256) void tab_kernel(
    float* __restrict__ x, const float* __restrict__ g,
    const float* __restrict__ b, const float* __restrict__ wq,
    const float* __restrict__ cq, float* __restrict__ outA, float* __restrict__ outB,
    const float* __restrict__ wk, const float* __restrict__ ck,
    float* __restrict__ outG, float* __restrict__ outD, int mode) {
  __shared__ float ys[TROWS][132];
  __shared__ float ws[32][132];
  const int tid = threadIdx.x;
  for (int t = tid; t < 2048; t += 256) ws[t >> 7][t & 127] = wq[t];
  for (int t = tid; t < 2048; t += 256) ws[16 + (t >> 7)][t & 127] = wk[t];
  const int wv = tid >> 6, lane = tid & 63;
  const int base = blockIdx.x * TROWS;
  {
    float2 gg = ((const float2*)g)[lane];
    float2 bb = ((const float2*)b)[lane];
    for (int t = 0; t < TROWS / 4; ++t) {
      const int r = wv * (TROWS / 4) + t;
      float2* xp = (float2*)(x + (size_t)(base + r) * 128);
      float2 v = xp[lane];
      float s1 = v.x + v.y, s2 = v.x * v.x + v.y * v.y;
#pragma unroll
      for (int k = 1; k < 64; k <<= 1) {
        s1 += __shfl_xor(s1, k);
        s2 += __shfl_xor(s2, k);
      }
      float mean = s1 * (1.f / 128.f);
      float var = s2 * (1.f / 128.f) - mean * mean;
      float rstd = rsqrtf(var + 1e-5f);
      float y0 = (v.x - mean) * rstd * gg.x + bb.x;
      float y1 = (v.y - mean) * rstd * gg.y + bb.y;
      xp[lane] = make_float2(y0, y1);   // in-place LN write-back
      ys[r][2 * lane] = y0;
      ys[r][2 * lane + 1] = y1;
    }
  }
  __syncthreads();
  // GEMV: 32 table cols x TROWS rows; thread = (col, row-group of 4)
  const int c = tid & 31;
  const int rg = (tid >> 5) * 4;
  const int side = c >> 4, oo = c & 15;
  const float* wrow = ws[c];
  const int val = oo >> 3, e = oo & 7;
  const float cadd = side ? ck[val * 8 + e] : cq[val * 8 + e];
  float* dst = side ? (val ? outD : outG) : (val ? outB : outA);
#pragma unroll
  for (int rr = 0; rr < 4; ++rr) {
    const int p = base + rg + rr;
    const int half = (p >= ROWS_) ? 1 : 0;
    const int ploc = p - half * ROWS_;
    const bool active = (mode == 0) || (half ? (side == 0) : (side == 1));
    if (active) {
      const float* yr = ys[rg + rr];
      float a0 = 0.f, a1 = 0.f, a2 = 0.f, a3 = 0.f;
#pragma unroll 4
      for (int f = 0; f < 128; f += 4) {
        a0 += yr[f] * wrow[f];
        a1 += yr[f + 1] * wrow[f + 1];
        a2 += yr[f + 2] * wrow[f + 2];
        a3 += yr[f + 3] * wrow[f + 3];
      }
      float acc = (a0 + a1) + (a2 + a3);
      int i = ploc >> 7, blow = ploc & 127;
      int b_out = (mode == 0) ? half * 128 + blow : blow;
      dst[((size_t)(b_out * 8 + e)) * 224 + i] = acc + cadd;
    }
  }
}

// ---------------------------------------------------------------------------
// Plain 64x64-tile bf16 MFMA GEMM (bf16 A input):
// mode 4: fout += acc + bias (out-proj residual); mode 5: fout = acc + bias.
// ---------------------------------------------------------------------------
__global__ __launch_bounds__(256) void gemm_plain(
    const u16* __restrict__ A, const u16* __restrict__ B,
    const float* __restrict__ bias, int mode, float* __restrict__ fout) {
  __shared__ u16 As[64 * 136];
  __shared__ u16 Bs[64 * 136];
  const int tid = threadIdx.x;
  const int M0 = blockIdx.x * 64, N0 = blockIdx.y * 64;
  const uint4* Ag = (const uint4*)(A + (size_t)M0 * 128);
  const uint4* Bg = (const uint4*)(B + (size_t)N0 * 128);
  for (int t = tid; t < 1024; t += 256) {
    int row = t >> 4, cc = t & 15;
    *(uint4*)&As[row * 136 + cc * 8] = Ag[row * 16 + cc];
  }
  for (int t = tid; t < 1024; t += 256) {
    int row = t >> 4, cc = t & 15;
    *(uint4*)&Bs[row * 136 + cc * 8] = Bg[row * 16 + cc];
  }
  __syncthreads();
  const int wave = tid >> 6, lane = tid & 63;
  const int wm = (wave >> 1) * 32, wn = (wave & 1) * 32;
  const int lr = lane & 15, kq = (lane >> 4) * 8;
  f32x4 acc[2][2] = {};
#pragma unroll
  for (int ks = 0; ks < 4; ++ks) {
    int ko = ks * 32 + kq;
    bf16x8 a0 = *(const bf16x8*)&As[(wm + lr) * 136 + ko];
    bf16x8 a1 = *(const bf16x8*)&As[(wm + 16 + lr) * 136 + ko];
    bf16x8 b0 = *(const bf16x8*)&Bs[(wn + lr) * 136 + ko];
    bf16x8 b1 = *(const bf16x8*)&Bs[(wn + 16 + lr) * 136 + ko];
    acc[0][0] = __builtin_amdgcn_mfma_f32_16x16x32_bf16(a0, b0, acc[0][0], 0, 0, 0);
    acc[0][1] = __builtin_amdgcn_mfma_f32_16x16x32_bf16(a0, b1, acc[0][1], 0, 0, 0);
    acc[1][0] = __builtin_amdgcn_mfma_f32_16x16x32_bf16(a1, b0, acc[1][0], 0, 0, 0);
    acc[1][1] = __builtin_amdgcn_mfma_f32_16x16x32_bf16(a1, b1, acc[1][1], 0, 0, 0);
  }
  const int colq = lane & 15, rowq = (lane >> 4) * 4;
#pragma unroll
  for (int tm = 0; tm < 2; ++tm)
#pragma unroll
    for (int tn = 0; tn < 2; ++tn) {
#pragma unroll
      for (int r = 0; r < 4; ++r) {
        int row = M0 + wm + tm * 16 + rowq + r;
        int col = N0 + wn + tn * 16 + colq;
        float v = acc[tm][tn][r] + bias[col];
        if (mode == 4) fout[(size_t)row * 128 + col] += v;
        else           fout[(size_t)row * 128 + col] = v;
      }
    }
}

// ---------------------------------------------------------------------------
// Self QKV GEMM: A-tile read from LN'd fp32 X, converted bf16 in-register.
// Grid (896, 6); rows cover xl+xr (row >= ROWS_ -> b += 128).
// ---------------------------------------------------------------------------
__global__ __launch_bounds__(256) void gemm_qkv_self(
    const float* __restrict__ X, const u16* __restrict__ Bw,
    const float* __restrict__ bias, u16* __restrict__ o0, u16* __restrict__ o1,
    u16* __restrict__ o2) {
  __shared__ u16 As[64 * 136];
  __shared__ u16 Bs[64 * 136];
  const int tid = threadIdx.x;
  const int M0 = blockIdx.x * 64, N0 = blockIdx.y * 64;
  {
    const uint4* Bg = (const uint4*)(Bw + (size_t)N0 * 128);
    for (int t = tid; t < 1024; t += 256) {
      int row = t >> 4, cc = t & 15;
      *(uint4*)&Bs[row * 136 + cc * 8] = Bg[row * 16 + cc];
    }
  }
  {
    const int wv = tid >> 6, lane = tid & 63;
    for (int t = 0; t < 16; ++t) {
      const int r = wv * 16 + t;
      float2 v = *(const float2*)&X[(size_t)(M0 + r) * 128 + lane * 2];
      ((u32*)As)[r * 68 + lane] = (u32)f2bf(v.x) | ((u32)f2bf(v.y) << 16);
    }
  }
  __syncthreads();
  const int wave = tid >> 6, lane = tid & 63;
  const int wm = (wave >> 1) * 32, wn = (wave & 1) * 32;
  const int lr = lane & 15, kq = (lane >> 4) * 8;
  f32x4 acc[2][2] = {};
#pragma unroll
  for (int ks = 0; ks < 4; ++ks) {
    int ko = ks * 32 + kq;
    bf16x8 a0 = *(const bf16x8*)&As[(wm + lr) * 136 + ko];
    bf16x8 a1 = *(const bf16x8*)&As[(wm + 16 + lr) * 136 + ko];
    bf16x8 b0 = *(const bf16x8*)&Bs[(wn + lr) * 136 + ko];
    bf16x8 b1 = *(const bf16x8*)&Bs[(wn + 16 + lr) * 136 + ko];
    acc[0][0] = __builtin_amdgcn_mfma_f32_16x16x32_bf16(a0, b0, acc[0][0], 0, 0, 0);
    acc[0][1] = __builtin_amdgcn_mfma_f32_16x16x32_bf16(a0, b1, acc[0][1], 0, 0, 0);
    acc[1][0] = __builtin_amdgcn_mfma_f32_16x16x32_bf16(a1, b0, acc[1][0], 0, 0, 0);
    acc[1][1] = __builtin_amdgcn_mfma_f32_16x16x32_bf16(a1, b1, acc[1][1], 0, 0, 0);
  }
  const int colq = lane & 15, rowq = (lane >> 4) * 4;
#pragma unroll
  for (int tm = 0; tm < 2; ++tm)
#pragma unroll
    for (int tn = 0; tn < 2; ++tn) {
#pragma unroll
      for (int r = 0; r < 4; ++r) {
        int row = M0 + wm + tm * 16 + rowq + r;
        int col = N0 + wn + tn * 16 + colq;
        float v = acc[tm][tn][r] + bias[col];
        int part = col >> 7;
        int cc = col & 127;
        int e = cc >> 4, c = cc & 15;
        int rloc = row, badd = 0;
        if (row >= ROWS_) { rloc = row - ROWS_; badd = 128; }
        int b = (rloc & 127) + badd, pos = rloc >> 7;
        size_t off = ((size_t)(b * NH + e) * W_ + pos) * HD + c;
        if (part == 0)      o0[off] = f2bf(v * 0.25f);
        else if (part == 1) o1[off] = f2bf(v);
        else                o2[off] = f2bf(v);
      }
    }
}

// ---------------------------------------------------------------------------
// Cross QKV GEMM, merged q+kv. Grid (448, 6):
// y<2: A = Xr (LN'd fp32), q scatter (*0.25). y>=2: A = Xl, k/v scatter.
// ---------------------------------------------------------------------------
__global__ __launch_bounds__(256) void gemm_qkv_cross(
    const float* __restrict__ Xl, const float* __restrict__ Xr,
    const u16* __restrict__ cWi, const float* __restrict__ cbi,
    u16* __restrict__ QB, u16* __restrict__ KB, u16* __restrict__ VB) {
  __shared__ u16 As[64 * 136];
  __shared__ u16 Bs[64 * 136];
  const int tid = threadIdx.x;
  const int M0 = blockIdx.x * 64;
  const int y = blockIdx.y;
  const bool isq = (y < 2);
  const float* X = isq ? Xr : Xl;
  const u16* Bw = isq ? cWi : cWi + 128 * 128;
  const float* bias = isq ? cbi : cbi + 128;
  const int N0 = (isq ? y : y - 2) * 64;
  {
    const uint4* Bg = (const uint4*)(Bw + (size_t)N0 * 128);
    for (int t = tid; t < 1024; t += 256) {
      int row = t >> 4, cc = t & 15;
      *(uint4*)&Bs[row * 136 + cc * 8] = Bg[row * 16 + cc];
    }
  }
  {
    const int wv = tid >> 6, lane = tid & 63;
    for (int t = 0; t < 16; ++t) {
      const int r = wv * 16 + t;
      float2 v = *(const float2*)&X[(size_t)(M0 + r) * 128 + lane * 2];
      ((u32*)As)[r * 68 + lane] = (u32)f2bf(v.x) | ((u32)f2bf(v.y) << 16);
    }
  }
  __syncthreads();
  const int wave = tid >> 6, lane = tid & 63;
  const int wm = (wave >> 1) * 32, wn = (wave & 1) * 32;
  const int lr = lane & 15, kq = (lane >> 4) * 8;
  f32x4 acc[2][2] = {};
#pragma unroll
  for (int ks = 0; ks < 4; ++ks) {
    int ko = ks * 32 + kq;
    bf16x8 a0 = *(const bf16x8*)&As[(wm + lr) * 136 + ko];
    bf16x8 a1 = *(const bf16x8*)&As[(wm + 16 + lr) * 136 + ko];
    bf16x8 b0 = *(const bf16x8*)&Bs[(wn + lr) * 136 + ko];
    bf16x8 b1 = *(const bf16x8*)&Bs[(wn + 16 + lr) * 136 + ko];
    acc[0][0] = __builtin_amdgcn_mfma_f32_16x16x32_bf16(a0, b0, acc[0][0], 0, 0, 0);
    acc[0][1] = __builtin_amdgcn_mfma_f32_16x16x32_bf16(a0, b1, acc[0][1], 0, 0, 0);
    acc[1][0] = __builtin_amdgcn_mfma_f32_16x16x32_bf16(a1, b0, acc[1][0], 0, 0, 0);
    acc[1][1] = __builtin_amdgcn_mfma_f32_16x16x32_bf16(a1, b1, acc[1][1], 0, 0, 0);
  }
  const int colq = lane & 15, rowq = (lane >> 4) * 4;
#pragma unroll
  for (int tm = 0; tm < 2; ++tm)
#pragma unroll
    for (int tn = 0; tn < 2; ++tn) {
#pragma unroll
      for (int r = 0; r < 4; ++r) {
        int row = M0 + wm + tm * 16 + rowq + r;
        int col = N0 + wn + tn * 16 + colq;
        float v = acc[tm][tn][r] + bias[col];
        int cc = col & 127;
        int e = cc >> 4, c = cc & 15;
        int b = row & 127, pos = row >> 7;
        size_t off = ((size_t)(b * NH + e) * W_ + pos) * HD + c;
        if (isq)                  QB[off] = f2bf(v * 0.25f);
        else if ((col >> 7) == 0) KB[off] = f2bf(v);
        else                      VB[off] = f2bf(v);
      }
    }
}

// ---------------------------------------------------------------------------
// MFMA flash attention per (head e, batch-row b). Two-pass softmax
// (register-resident S^T strip, exact max). PE affine term rides in 6
// zero-padded contraction slots.
// ---------------------------------------------------------------------------
__global__ __launch_bounds__(448) void attn_kernel(
    const u16* __restrict__ qb, const u16* __restrict__ kb,
    const u16* __restrict__ vb, const float* __restrict__ ALPHA,
    const float* __restrict__ BETA, const float* __restrict__ GAMMA,
    const float* __restrict__ DELTA, u16* __restrict__ obuf) {
  __shared__ u16 Ksh[224 * KSTR];
  __shared__ u16 Qsh[224 * KSTR];
  __shared__ u16 Vt[16 * VSTR];
  __shared__ u16 Pbuf[7][16 * KSTR];
  const int e = blockIdx.x, b = blockIdx.y;
  const size_t hb = (size_t)(b * NH + e);
  const int tid = threadIdx.x;
  const u32 ONE = 0x3F80u;

  if (tid < 224) {
    const int j = tid;
    const uint4* src = (const uint4*)(kb + (hb * W_ + j) * HD);
    uint4 a = src[0], b2 = src[1];
    *(uint4*)&Ksh[j * KSTR] = a;
    *(uint4*)&Ksh[j * KSTR + 8] = b2;
    float G = GAMMA[hb * 224 + j];
    float D = DELTA[hb * 224 + j];
    float jf = (float)j;
    float P = G * jf + D;
    u16 Phi = f2bf(P);
    float Plo = P - __uint_as_float((u32)Phi << 16);
    u32* ex = (u32*)&Ksh[j * KSTR + 16];
    ex[0] = (u32)f2bf(G) | ((u32)Phi << 16);
    ex[1] = (u32)f2bf(Plo) | ((u32)f2bf(jf) << 16);
    ex[2] = ONE | (ONE << 16);
#pragma unroll
    for (int z = 3; z < 12; ++z) ex[z] = 0;
    const uint4* vsrc = (const uint4*)(vb + (hb * W_ + j) * HD);
    uint4 va = vsrc[0], vb4 = vsrc[1];
    u32 w[8] = {va.x, va.y, va.z, va.w, vb4.x, vb4.y, vb4.z, vb4.w};
#pragma unroll
    for (int c = 0; c < 16; ++c)
      Vt[c * VSTR + j] = (c & 1) ? (u16)(w[c >> 1] >> 16) : (u16)(w[c >> 1] & 0xFFFF);
  } else {
    const int i = tid - 224;
    const uint4* src = (const uint4*)(qb + (hb * W_ + i) * HD);
    uint4 a = src[0], b2 = src[1];
    *(uint4*)&Qsh[i * KSTR] = a;
    *(uint4*)&Qsh[i * KSTR + 8] = b2;
    float al = ALPHA[hb * 224 + i];
    float be = BETA[hb * 224 + i];
    float ifl = (float)i;
    float Q = be - al * ifl;
    u16 Qhi = f2bf(Q);
    float Qlo = Q - __uint_as_float((u32)Qhi << 16);
    u32* ex = (u32*)&Qsh[i * KSTR + 16];
    ex[0] = (u32)f2bf(-ifl) | (ONE << 16);
    ex[1] = ONE | ((u32)f2bf(al) << 16);
    ex[2] = (u32)Qhi | ((u32)f2bf(Qlo) << 16);
#pragma unroll
    for (int z = 3; z < 12; ++z) ex[z] = 0;
  }
  __syncthreads();

  const int wid = tid >> 6, lane = tid & 63;
  const int g = lane >> 4, li = lane & 15;
  u16* pb = &Pbuf[wid][0];
  const int obase = (b & 128) ? ROWS_ : 0;
  const int blow = b & 127;

  for (int qt = wid * 2; qt < wid * 2 + 2; ++qt) {
    const int i0 = qt * 16;
    const bf16x8 Bq = *(const bf16x8*)&Qsh[(i0 + li) * KSTR + g * 8];
    f32x4 C[7][2];
#pragma unroll
    for (int js = 0; js < 7; ++js) {
      const bf16x8 A0 = *(const bf16x8*)&Ksh[(js * 32 + li) * KSTR + g * 8];
      const bf16x8 A1 = *(const bf16x8*)&Ksh[(js * 32 + 16 + li) * KSTR + g * 8];
      const f32x4 Z = {0.f, 0.f, 0.f, 0.f};
      C[js][0] = __builtin_amdgcn_mfma_f32_16x16x32_bf16(A0, Bq, Z, 0, 0, 0);
      C[js][1] = __builtin_amdgcn_mfma_f32_16x16x32_bf16(A1, Bq, Z, 0, 0, 0);
    }
    float m = -1e30f;
#pragma unroll
    for (int js = 0; js < 7; ++js)
#pragma unroll
      for (int h = 0; h < 2; ++h)
        m = fmaxf(m, fmaxf(fmaxf(C[js][h][0], C[js][h][1]), fmaxf(C[js][h][2], C[js][h][3])));
    m = fmaxf(m, __shfl_xor(m, 16));
    m = fmaxf(m, __shfl_xor(m, 32));
    f32x4 O = {0.f, 0.f, 0.f, 0.f};
    float lsum = 0.f;
#pragma unroll
    for (int js = 0; js < 7; ++js) {
      float p0 = __expf(C[js][0][0] - m), p1 = __expf(C[js][0][1] - m);
      float p2 = __expf(C[js][0][2] - m), p3 = __expf(C[js][0][3] - m);
      float p4 = __expf(C[js][1][0] - m), p5 = __expf(C[js][1][1] - m);
      float p6 = __expf(C[js][1][2] - m), p7 = __expf(C[js][1][3] - m);
      lsum += ((p0 + p1) + (p2 + p3)) + ((p4 + p5) + (p6 + p7));
      u16* pr = pb + li * KSTR + g * 4;
      pr[0] = f2bf(p0); pr[1] = f2bf(p1); pr[2] = f2bf(p2); pr[3] = f2bf(p3);
      pr[16] = f2bf(p4); pr[17] = f2bf(p5); pr[18] = f2bf(p6); pr[19] = f2bf(p7);
      const bf16x8 Ap = *(const bf16x8*)&Pbuf[wid][li * KSTR + g * 8];
      const bf16x8 Bv = *(const bf16x8*)&Vt[li * VSTR + js * 32 + g * 8];
      O = __builtin_amdgcn_mfma_f32_16x16x32_bf16(Ap, Bv, O, 0, 0, 0);
    }
    lsum += __shfl_xor(lsum, 16);
    lsum += __shfl_xor(lsum, 32);
#pragma unroll
    for (int r = 0; r < 4; ++r) {
      const float lr = __shfl(lsum, g * 4 + r);
      const int irow = i0 + g * 4 + r;
      obuf[((size_t)(obase + irow * 128 + blow)) * C_ + e * HD + li] = f2bf(O[r] * (1.f / lr));
    }
  }
}

// Gather x_l/x_r[b][c][h][w] -> bf16 rows p = img*28672 + w*128 + h*2 + b.
__global__ __launch_bounds__(256) void transpose_kernel(const float* __restrict__ x_l,
                                                        const float* __restrict__ x_r,
                                                        u16* __restrict__ xT) {
  __shared__ float tile[128][57];
  const int wt = blockIdx.x * 56, hi = blockIdx.y;
  const int img = blockIdx.z >> 1, bi = blockIdx.z & 1;
  const float* x = img ? x_r : x_l;
  const int wave = threadIdx.x >> 6, lane = threadIdx.x & 63;
  for (int c = wave; c < 128; c += 4) {
    if (lane < 56)
      tile[c][lane] = x[(((size_t)bi * 128 + c) * 64 + hi) * 224 + wt + lane];
  }
  __syncthreads();
  u32* dst = (u32*)xT;
  for (int w = wave; w < 56; w += 4) {
    int p = img * ROWS_ + (wt + w) * 128 + hi * 2 + bi;
    float a = tile[lane * 2][w], b2 = tile[lane * 2 + 1][w];
    dst[(size_t)p * 64 + lane] = (u32)f2bf(a) | ((u32)f2bf(b2) << 16);
  }
}

// ---------------------------------------------------------------------------
// Final soft-argmax over recomputed layer-5 cross logits.
// ---------------------------------------------------------------------------
__global__ __launch_bounds__(448) void corresp_kernel(
    const u16* __restrict__ qb, const u16* __restrict__ kb,
    const float* __restrict__ ALPHA, const float* __restrict__ BETA,
    const float* __restrict__ GAMMA, const float* __restrict__ DELTA,
    float* __restrict__ out) {
  __shared__ __align__(16) u32 Ks[224 * 68];
  __shared__ float Gs[224], Ds[224];
  const int b = blockIdx.x, tid = threadIdx.x;
  const u32* kg = (const u32*)kb;
  for (int t = tid; t < 224 * 64; t += 448) {
    int row = t >> 6, col = t & 63;
    Ks[row * 68 + col] = kg[((size_t)(b * 8 + (col >> 3)) * 224 + row) * 8 + (col & 7)];
  }
  if (tid < 224) {
    float gs = 0.f, ds = 0.f;
#pragma unroll
    for (int e = 0; e < 8; ++e) {
      gs += GAMMA[((size_t)(b * 8 + e)) * 224 + tid];
      ds += DELTA[((size_t)(b * 8 + e)) * 224 + tid];
    }
    Gs[tid] = gs;
    Ds[tid] = ds;
  }
  __syncthreads();
  const int ii = tid >> 2, jq = tid & 3;
  const int i = blockIdx.y * 112 + ii;
  float qf[128];
  const u32* qg = (const u32*)qb;
#pragma unroll
  for (int uu = 0; uu < 64; ++uu) {
    u32 qv = qg[((size_t)(b * 8 + (uu >> 3)) * 224 + i) * 8 + (uu & 7)];
    qf[2 * uu] = bflo(qv);
    qf[2 * uu + 1] = bfhi(qv);
  }
  float ai = 0.f, bi_ = 0.f;
#pragma unroll
  for (int e = 0; e < 8; ++e) {
    ai += ALPHA[((size_t)(b * 8 + e)) * 224 + i];
    bi_ += BETA[((size_t)(b * 8 + e)) * 224 + i];
  }
  float m = -1e30f, l = 0.f, wj = 0.f;
  for (int jj = 0; jj < 56; ++jj) {
    int jo = jj + jq * 14;
    if (jo >= 56) jo -= 56;
    const int j = jq * 56 + jo;
    const u32* kr = &Ks[j * 68];
    float p0 = 0.f, p1 = 0.f, p2 = 0.f, p3 = 0.f;
#pragma unroll
    for (int w = 0; w < 16; ++w) {
      uint4 kk = *(const uint4*)&kr[w * 4];
      p0 += qf[w * 8 + 0] * bflo(kk.x) + qf[w * 8 + 1] * bfhi(kk.x);
      p1 += qf[w * 8 + 2] * bflo(kk.y) + qf[w * 8 + 3] * bfhi(kk.y);
      p2 += qf[w * 8 + 4] * bflo(kk.z) + qf[w * 8 + 5] * bfhi(kk.z);
      p3 += qf[w * 8 + 6] * bflo(kk.w) + qf[w * 8 + 7] * bfhi(kk.w);
    }
    float s = (p0 + p1) + (p2 + p3);
    s += (float)(j - i) * (ai + Gs[j]) + bi_ + Ds[j];
    if (s > m) {
      float fs = __expf(m - s);
      l *= fs;
      wj *= fs;
      m = s;
    }
    float p = __expf(s - m);
    l += p;
    wj += p * (float)j;
  }
#pragma unroll
  for (int r = 1; r <= 2; r <<= 1) {
    float mo = __shfl_xor(m, r);
    float m2 = fmaxf(m, mo);
    float fa = __expf(m - m2), fb = __expf(mo - m2);
    l = l * fa + __shfl_xor(l, r) * fb;
    wj = wj * fa + __shfl_xor(wj, r) * fb;
    m = m2;
  }
  if (jq == 0) out[(size_t)b * 224 + i] = (float)i - wj / fmaxf(l, 1e-30f);
}

// Single-launch conversion of all five weight tensors to one bf16 buffer.
#define OFF_FEAT 0
#define OFF_SWI 16384
#define OFF_SWO 311296
#define OFF_CWI 409600
#define OFF_CWO 704512
#define N_WALL 802816
__global__ __launch_bounds__(256) void cvt_all_kernel(
    const float* __restrict__ feat_w, const float* __restrict__ self_Wi,
    const float* __restrict__ self_Wo, const float* __restrict__ cross_Wi,
    const float* __restrict__ cross_Wo, u16* __restrict__ dst) {
  int idx = blockIdx.x * 256 + threadIdx.x;
  if (idx >= N_WALL) return;
  float v;
  if (idx < OFF_SWI)       v = feat_w[idx];
  else if (idx < OFF_SWO)  v = self_Wi[idx - OFF_SWI];
  else if (idx < OFF_CWI)  v = self_Wo[idx - OFF_SWO];
  else if (idx < OFF_CWO)  v = cross_Wi[idx - OFF_CWI];
  else                     v = cross_Wo[idx - OFF_CWO];
  dst[idx] = f2bf(v);
}

extern "C" void kernel_launch(void* const* d_in, const int* in_sizes, int n_in,
                              void* d_out, int out_size, void* d_ws, size_t ws_size,
                              hipStream_t stream) {
  (void)in_sizes; (void)n_in; (void)out_size; (void)ws_size;
  const float* x_l = (const float*)d_in[0];
  const float* x_r = (const float*)d_in[1];
  const float* feat_w = (const float*)d_in[2];
  const float* feat_b = (const float*)d_in[3];
  const float* self_Wi = (const float*)d_in[4];
  const float* self_bi = (const float*)d_in[5];
  const float* self_Wo = (const float*)d_in[6];
  const float* self_bo = (const float*)d_in[7];
  const float* cross_Wi = (const float*)d_in[8];
  const float* cross_bi = (const float*)d_in[9];
  const float* cross_Wo = (const float*)d_in[10];
  const float* cross_bo = (const float*)d_in[11];
  const float* ln_g = (const float*)d_in[12];
  const float* ln_b = (const float*)d_in[13];

  char* ws = (char*)d_ws;
  size_t off = 0;
  auto alloc = [&](size_t bytes) {
    char* p = ws + off;
    off += (bytes + 255) & ~(size_t)255;
    return p;
  };
  // Total ~97 MB — under the R6-proven ~112 MB budget (R7/R8 lesson).
  float* XA = (float*)alloc((size_t)2 * ROWS_ * C_ * 4);   // residual (in-place LN)
  u16* QB = (u16*)alloc((size_t)256 * NH * W_ * HD * 2);   // also XT scratch
  u16* KB = (u16*)alloc((size_t)256 * NH * W_ * HD * 2);
  u16* VB = (u16*)alloc((size_t)256 * NH * W_ * HD * 2);
  u16* OB = (u16*)alloc((size_t)2 * ROWS_ * C_ * 2);
  u16* WALL = (u16*)alloc((size_t)N_WALL * 2);
  float* PREP = (float*)alloc((size_t)12 * PREP_STRIDE * 4);
  float* ALPHA = (float*)alloc((size_t)256 * NH * W_ * 4);
  float* BETA = (float*)alloc((size_t)256 * NH * W_ * 4);
  float* GAMMA = (float*)alloc((size_t)256 * NH * W_ * 4);
  float* DELTA = (float*)alloc((size_t)256 * NH * W_ * 4);

  cvt_all_kernel<<<3136, 256, 0, stream>>>(feat_w, self_Wi, self_Wo, cross_Wi, cross_Wo, WALL);
  prep_kernel<<<12, 256, 0, stream>>>(self_Wi, self_bi, cross_Wi, cross_bi, PREP);

  transpose_kernel<<<dim3(4, 64, 4), 256, 0, stream>>>(x_l, x_r, QB);
  gemm_plain<<<dim3(896, 2), 256, 0, stream>>>(QB, WALL + OFF_FEAT, feat_b, 5, XA);

  for (int l = 0; l < 6; ++l) {
    const u16* sWi = WALL + OFF_SWI + (size_t)l * 384 * 128;
    const u16* sWo = WALL + OFF_SWO + (size_t)l * 128 * 128;
    const u16* cWi = WALL + OFF_CWI + (size_t)l * 384 * 128;
    const u16* cWo = WALL + OFF_CWO + (size_t)l * 128 * 128;
    const float* sbi = self_bi + l * 384;
    const float* sbo = self_bo + l * 128;
    const float* cbi = cross_bi + l * 384;
    const float* cbo = cross_bo + l * 128;
    const float* ps = PREP + (size_t)(l * 2) * PREP_STRIDE;
    const float* pc = PREP + (size_t)(l * 2 + 1) * PREP_STRIDE;

    // --- self attention on xl AND xr: X = LN(X) (+tables), qkv, attn, +=proj ---
    tab_kernel<<<1792, 256, 0, stream>>>(XA, ln_g, ln_b, ps, ps + 4096, ALPHA, BETA,
                                         ps + 2048, ps + 4112, GAMMA, DELTA, 0);
    gemm_qkv_self<<<dim3(896, 6), 256, 0, stream>>>(XA, sWi, sbi, QB, KB, VB);
    attn_kernel<<<dim3(8, 256), 448, 0, stream>>>(QB, KB, VB, ALPHA, BETA, GAMMA, DELTA, OB);
    gemm_plain<<<dim3(896, 2), 256, 0, stream>>>(OB, sWo, sbo, 4, XA);

    // --- cross attention: q from xr, k/v from xl; X = LN(X) first ---
    tab_kernel<<<1792, 256, 0, stream>>>(XA, ln_g, ln_b, pc, pc + 4096, ALPHA, BETA,
                                         pc + 2048, pc + 4112, GAMMA, DELTA, 1);
    gemm_qkv_cross<<<dim3(448, 6), 256, 0, stream>>>(XA, XA + (size_t)ROWS_ * C_, cWi, cbi,
                                                     QB, KB, VB);
    if (l < 5) {
      attn_kernel<<<dim3(8, 128), 448, 0, stream>>>(QB, KB, VB, ALPHA, BETA, GAMMA, DELTA, OB);
      gemm_plain<<<dim3(448, 2), 256, 0, stream>>>(OB, cWo, cbo, 4, XA);  // xl half only
    }
    // l == 5: attention output / x updates dead; corresp reads QB/KB + tables.
  }
  corresp_kernel<<<dim3(128, 2), 448, 0, stream>>>(QB, KB, ALPHA, BETA, GAMMA, DELTA,
                                                   (float*)d_out);
}

// Round 11
// 1347.511 us; speedup vs baseline: 1.4182x; 1.0729x over previous
//
#include <hip/hip_runtime.h>

typedef unsigned short u16;
typedef unsigned int u32;

#define W_ 224
#define H_ 128
#define C_ 128
#define NH 8
#define HD 16
#define ROWS_ (W_ * H_)          // 28672 rows per image
#define PREP_STRIDE 4128
#define KSTR 40
#define VSTR 232
#define TROWS 32                 // rows per tab_kernel block

typedef __bf16 bf16x8 __attribute__((ext_vector_type(8)));
typedef float f32x4 __attribute__((ext_vector_type(4)));

__device__ __forceinline__ u16 f2bf(float f) {
  u32 u = __float_as_uint(f);
  return (u16)((u + 0x7FFFu + ((u >> 16) & 1u)) >> 16);
}
__device__ __forceinline__ float bflo(u32 u) { return __uint_as_float(u << 16); }
__device__ __forceinline__ float bfhi(u32 u) { return __uint_as_float(u & 0xFFFF0000u); }

// ---------------------------------------------------------------------------
// Rank-1 PE decomposition prep: rpe[d] = (d-223)*(W u) + b -> per-row affine.
// ---------------------------------------------------------------------------
__global__ __launch_bounds__(256) void prep_kernel(
    const float* __restrict__ self_Wi, const float* __restrict__ self_bi,
    const float* __restrict__ cross_Wi, const float* __restrict__ cross_bi,
    float* __restrict__ prep) {
  __shared__ float u[128];
  __shared__ float A[256];
  const int s = blockIdx.x, l = s >> 1;
  const float* Wi = (s & 1) ? cross_Wi + (size_t)l * 384 * 128 : self_Wi + (size_t)l * 384 * 128;
  const float* bi = (s & 1) ? cross_bi + l * 384 : self_bi + l * 384;
  const int tid = threadIdx.x;
  if (tid < 128) {
    float ex = (float)(tid & ~1) * (1.f / 128.f);
    u[tid] = expf(-ex * logf(10000.f));
  }
  __syncthreads();
  {
    float a = 0.f;
    const float* wr = Wi + (size_t)tid * 128;
    for (int f = 0; f < 128; ++f) a += wr[f] * u[f];
    A[tid] = a;
  }
  __syncthreads();
  float* out = prep + (size_t)s * PREP_STRIDE;
  for (int t = tid; t < 4096; t += 256) {
    int v = t >> 10, e = (t >> 7) & 7, f = t & 127;
    float acc = 0.f;
#pragma unroll
    for (int c = 0; c < 16; ++c) {
      int qrow = e * 16 + c, krow = 128 + e * 16 + c;
      if (v == 0)      acc += Wi[(size_t)qrow * 128 + f] * A[krow];
      else if (v == 1) acc += Wi[(size_t)qrow * 128 + f] * bi[krow];
      else if (v == 2) acc += Wi[(size_t)krow * 128 + f] * A[qrow];
      else             acc += Wi[(size_t)krow * 128 + f] * bi[qrow];
    }
    out[t] = acc * 0.25f;
  }
  if (tid < 32) {
    int v = tid >> 3, e = tid & 7;
    float acc = 0.f;
#pragma unroll
    for (int c = 0; c < 16; ++c) {
      int qrow = e * 16 + c, krow = 128 + e * 16 + c;
      if (v == 0)      acc += bi[qrow] * A[krow];
      else if (v == 1) acc += bi[qrow] * bi[krow];
      else if (v == 2) acc += bi[krow] * A[qrow];
      else             acc += bi[krow] * bi[qrow];
    }
    out[4096 + tid] = acc * 0.25f;
  }
}

// ---------------------------------------------------------------------------
// Fused LN + affine-PE tables, 32 rows per block. X = LN(X) in place + fp32
// alpha/beta/gamma/delta tables. mode 0 self, mode 1 cross.
// ---------------------------------------------------------------------------
__global__ __launch_bounds__(256) void tab_kernel(
    float* __restrict__ x, const float* __restrict__ g,
    const float* __restrict__ b, const float* __restrict__ wq,
    const float* __restrict__ cq, float* __restrict__ outA, float* __restrict__ outB,
    const float* __restrict__ wk, const float* __restrict__ ck,
    float* __restrict__ outG, float* __restrict__ outD, int mode) {
  __shared__ float ys[TROWS][132];
  __shared__ float ws[32][132];
  const int tid = threadIdx.x;
  for (int t = tid; t < 2048; t += 256) ws[t >> 7][t & 127] = wq[t];
  for (int t = tid; t < 2048; t += 256) ws[16 + (t >> 7)][t & 127] = wk[t];
  const int wv = tid >> 6, lane = tid & 63;
  const int base = blockIdx.x * TROWS;
  {
    float2 gg = ((const float2*)g)[lane];
    float2 bb = ((const float2*)b)[lane];
    for (int t = 0; t < TROWS / 4; ++t) {
      const int r = wv * (TROWS / 4) + t;
      float2* xp = (float2*)(x + (size_t)(base + r) * 128);
      float2 v = xp[lane];
      float s1 = v.x + v.y, s2 = v.x * v.x + v.y * v.y;
#pragma unroll
      for (int k = 1; k < 64; k <<= 1) {
        s1 += __shfl_xor(s1, k);
        s2 += __shfl_xor(s2, k);
      }
      float mean = s1 * (1.f / 128.f);
      float var = s2 * (1.f / 128.f) - mean * mean;
      float rstd = rsqrtf(var + 1e-5f);
      float y0 = (v.x - mean) * rstd * gg.x + bb.x;
      float y1 = (v.y - mean) * rstd * gg.y + bb.y;
      xp[lane] = make_float2(y0, y1);   // in-place LN write-back
      ys[r][2 * lane] = y0;
      ys[r][2 * lane + 1] = y1;
    }
  }
  __syncthreads();
  const int c = tid & 31;
  const int rg = (tid >> 5) * 4;
  const int side = c >> 4, oo = c & 15;
  const float* wrow = ws[c];
  const int val = oo >> 3, e = oo & 7;
  const float cadd = side ? ck[val * 8 + e] : cq[val * 8 + e];
  float* dst = side ? (val ? outD : outG) : (val ? outB : outA);
#pragma unroll
  for (int rr = 0; rr < 4; ++rr) {
    const int p = base + rg + rr;
    const int half = (p >= ROWS_) ? 1 : 0;
    const int ploc = p - half * ROWS_;
    const bool active = (mode == 0) || (half ? (side == 0) : (side == 1));
    if (active) {
      const float* yr = ys[rg + rr];
      float a0 = 0.f, a1 = 0.f, a2 = 0.f, a3 = 0.f;
#pragma unroll 4
      for (int f = 0; f < 128; f += 4) {
        a0 += yr[f] * wrow[f];
        a1 += yr[f + 1] * wrow[f + 1];
        a2 += yr[f + 2] * wrow[f + 2];
        a3 += yr[f + 3] * wrow[f + 3];
      }
      float acc = (a0 + a1) + (a2 + a3);
      int i = ploc >> 7, blow = ploc & 127;
      int b_out = (mode == 0) ? half * 128 + blow : blow;
      dst[((size_t)(b_out * 8 + e)) * 224 + i] = acc + cadd;
    }
  }
}

// ---------------------------------------------------------------------------
// Plain 64x64-tile bf16 MFMA GEMM (bf16 A input):
// mode 4: fout += acc + bias (out-proj residual); mode 5: fout = acc + bias.
// ---------------------------------------------------------------------------
__global__ __launch_bounds__(256) void gemm_plain(
    const u16* __restrict__ A, const u16* __restrict__ B,
    const float* __restrict__ bias, int mode, float* __restrict__ fout) {
  __shared__ u16 As[64 * 136];
  __shared__ u16 Bs[64 * 136];
  const int tid = threadIdx.x;
  const int M0 = blockIdx.x * 64, N0 = blockIdx.y * 64;
  const uint4* Ag = (const uint4*)(A + (size_t)M0 * 128);
  const uint4* Bg = (const uint4*)(B + (size_t)N0 * 128);
  for (int t = tid; t < 1024; t += 256) {
    int row = t >> 4, cc = t & 15;
    *(uint4*)&As[row * 136 + cc * 8] = Ag[row * 16 + cc];
  }
  for (int t = tid; t < 1024; t += 256) {
    int row = t >> 4, cc = t & 15;
    *(uint4*)&Bs[row * 136 + cc * 8] = Bg[row * 16 + cc];
  }
  __syncthreads();
  const int wave = tid >> 6, lane = tid & 63;
  const int wm = (wave >> 1) * 32, wn = (wave & 1) * 32;
  const int lr = lane & 15, kq = (lane >> 4) * 8;
  f32x4 acc[2][2] = {};
#pragma unroll
  for (int ks = 0; ks < 4; ++ks) {
    int ko = ks * 32 + kq;
    bf16x8 a0 = *(const bf16x8*)&As[(wm + lr) * 136 + ko];
    bf16x8 a1 = *(const bf16x8*)&As[(wm + 16 + lr) * 136 + ko];
    bf16x8 b0 = *(const bf16x8*)&Bs[(wn + lr) * 136 + ko];
    bf16x8 b1 = *(const bf16x8*)&Bs[(wn + 16 + lr) * 136 + ko];
    acc[0][0] = __builtin_amdgcn_mfma_f32_16x16x32_bf16(a0, b0, acc[0][0], 0, 0, 0);
    acc[0][1] = __builtin_amdgcn_mfma_f32_16x16x32_bf16(a0, b1, acc[0][1], 0, 0, 0);
    acc[1][0] = __builtin_amdgcn_mfma_f32_16x16x32_bf16(a1, b0, acc[1][0], 0, 0, 0);
    acc[1][1] = __builtin_amdgcn_mfma_f32_16x16x32_bf16(a1, b1, acc[1][1], 0, 0, 0);
  }
  const int colq = lane & 15, rowq = (lane >> 4) * 4;
#pragma unroll
  for (int tm = 0; tm < 2; ++tm)
#pragma unroll
    for (int tn = 0; tn < 2; ++tn) {
#pragma unroll
      for (int r = 0; r < 4; ++r) {
        int row = M0 + wm + tm * 16 + rowq + r;
        int col = N0 + wn + tn * 16 + colq;
        float v = acc[tm][tn][r] + bias[col];
        if (mode == 4) fout[(size_t)row * 128 + col] += v;
        else           fout[(size_t)row * 128 + col] = v;
      }
    }
}

// ---------------------------------------------------------------------------
// Self QKV GEMM: 64 rows x 128 cols per block (3 y-tiles — halves the fp32
// A-tile re-reads vs 64-col tiles). A read from LN'd fp32 X, bf16-converted
// in-register. Rows cover xl+xr (row >= ROWS_ -> b += 128).
// ---------------------------------------------------------------------------
__global__ __launch_bounds__(256) void gemm_qkv_self(
    const float* __restrict__ X, const u16* __restrict__ Bw,
    const float* __restrict__ bias, u16* __restrict__ o0, u16* __restrict__ o1,
    u16* __restrict__ o2) {
  __shared__ u16 As[64 * 136];
  __shared__ u16 Bs[128 * 136];
  const int tid = threadIdx.x;
  const int M0 = blockIdx.x * 64, N0 = blockIdx.y * 128;
  {
    const uint4* Bg = (const uint4*)(Bw + (size_t)N0 * 128);
    for (int t = tid; t < 2048; t += 256) {
      int row = t >> 4, cc = t & 15;
      *(uint4*)&Bs[row * 136 + cc * 8] = Bg[row * 16 + cc];
    }
  }
  {
    const int wv = tid >> 6, lane = tid & 63;
    for (int t = 0; t < 16; ++t) {
      const int r = wv * 16 + t;
      float2 v = *(const float2*)&X[(size_t)(M0 + r) * 128 + lane * 2];
      ((u32*)As)[r * 68 + lane] = (u32)f2bf(v.x) | ((u32)f2bf(v.y) << 16);
    }
  }
  __syncthreads();
  const int wave = tid >> 6, lane = tid & 63;
  const int wm = (wave >> 1) * 32, wn = (wave & 1) * 64;
  const int lr = lane & 15, kq = (lane >> 4) * 8;
  f32x4 acc[2][4] = {};
#pragma unroll
  for (int ks = 0; ks < 4; ++ks) {
    int ko = ks * 32 + kq;
    bf16x8 a0 = *(const bf16x8*)&As[(wm + lr) * 136 + ko];
    bf16x8 a1 = *(const bf16x8*)&As[(wm + 16 + lr) * 136 + ko];
#pragma unroll
    for (int tn = 0; tn < 4; ++tn) {
      bf16x8 b0 = *(const bf16x8*)&Bs[(wn + tn * 16 + lr) * 136 + ko];
      acc[0][tn] = __builtin_amdgcn_mfma_f32_16x16x32_bf16(a0, b0, acc[0][tn], 0, 0, 0);
      acc[1][tn] = __builtin_amdgcn_mfma_f32_16x16x32_bf16(a1, b0, acc[1][tn], 0, 0, 0);
    }
  }
  const int colq = lane & 15, rowq = (lane >> 4) * 4;
#pragma unroll
  for (int tm = 0; tm < 2; ++tm)
#pragma unroll
    for (int tn = 0; tn < 4; ++tn) {
#pragma unroll
      for (int r = 0; r < 4; ++r) {
        int row = M0 + wm + tm * 16 + rowq + r;
        int col = N0 + wn + tn * 16 + colq;
        float v = acc[tm][tn][r] + bias[col];
        int part = col >> 7;
        int cc = col & 127;
        int e = cc >> 4, c = cc & 15;
        int rloc = row, badd = 0;
        if (row >= ROWS_) { rloc = row - ROWS_; badd = 128; }
        int b = (rloc & 127) + badd, pos = rloc >> 7;
        size_t off = ((size_t)(b * NH + e) * W_ + pos) * HD + c;
        if (part == 0)      o0[off] = f2bf(v * 0.25f);
        else if (part == 1) o1[off] = f2bf(v);
        else                o2[off] = f2bf(v);
      }
    }
}

// ---------------------------------------------------------------------------
// Cross QKV GEMM: 64 rows x 128 cols per block, 3 y-tiles:
// y=0: q from Xr (*0.25); y=1: K from Xl; y=2: V from Xl.
// ---------------------------------------------------------------------------
__global__ __launch_bounds__(256) void gemm_qkv_cross(
    const float* __restrict__ Xl, const float* __restrict__ Xr,
    const u16* __restrict__ cWi, const float* __restrict__ cbi,
    u16* __restrict__ QB, u16* __restrict__ KB, u16* __restrict__ VB) {
  __shared__ u16 As[64 * 136];
  __shared__ u16 Bs[128 * 136];
  const int tid = threadIdx.x;
  const int M0 = blockIdx.x * 64;
  const int y = blockIdx.y;
  const float* X = (y == 0) ? Xr : Xl;
  const u16* Bw = cWi + (size_t)y * 128 * 128;
  const float* bias = cbi + y * 128;
  {
    const uint4* Bg = (const uint4*)Bw;
    for (int t = tid; t < 2048; t += 256) {
      int row = t >> 4, cc = t & 15;
      *(uint4*)&Bs[row * 136 + cc * 8] = Bg[row * 16 + cc];
    }
  }
  {
    const int wv = tid >> 6, lane = tid & 63;
    for (int t = 0; t < 16; ++t) {
      const int r = wv * 16 + t;
      float2 v = *(const float2*)&X[(size_t)(M0 + r) * 128 + lane * 2];
      ((u32*)As)[r * 68 + lane] = (u32)f2bf(v.x) | ((u32)f2bf(v.y) << 16);
    }
  }
  __syncthreads();
  const int wave = tid >> 6, lane = tid & 63;
  const int wm = (wave >> 1) * 32, wn = (wave & 1) * 64;
  const int lr = lane & 15, kq = (lane >> 4) * 8;
  f32x4 acc[2][4] = {};
#pragma unroll
  for (int ks = 0; ks < 4; ++ks) {
    int ko = ks * 32 + kq;
    bf16x8 a0 = *(const bf16x8*)&As[(wm + lr) * 136 + ko];
    bf16x8 a1 = *(const bf16x8*)&As[(wm + 16 + lr) * 136 + ko];
#pragma unroll
    for (int tn = 0; tn < 4; ++tn) {
      bf16x8 b0 = *(const bf16x8*)&Bs[(wn + tn * 16 + lr) * 136 + ko];
      acc[0][tn] = __builtin_amdgcn_mfma_f32_16x16x32_bf16(a0, b0, acc[0][tn], 0, 0, 0);
      acc[1][tn] = __builtin_amdgcn_mfma_f32_16x16x32_bf16(a1, b0, acc[1][tn], 0, 0, 0);
    }
  }
  u16* outp = (y == 0) ? QB : ((y == 1) ? KB : VB);
  const float scale = (y == 0) ? 0.25f : 1.f;
  const int colq = lane & 15, rowq = (lane >> 4) * 4;
#pragma unroll
  for (int tm = 0; tm < 2; ++tm)
#pragma unroll
    for (int tn = 0; tn < 4; ++tn) {
#pragma unroll
      for (int r = 0; r < 4; ++r) {
        int row = M0 + wm + tm * 16 + rowq + r;
        int col = wn + tn * 16 + colq;
        float v = (acc[tm][tn][r] + bias[col]) * scale;
        int e = col >> 4, c = col & 15;
        int b = row & 127, pos = row >> 7;
        outp[((size_t)(b * NH + e) * W_ + pos) * HD + c] = f2bf(v);
      }
    }
}

// ---------------------------------------------------------------------------
// MFMA flash attention per (head e, batch-row b). Two-pass softmax
// (register-resident S^T strip, exact max). PE affine term rides in 6
// zero-padded contraction slots.
// ---------------------------------------------------------------------------
__global__ __launch_bounds__(448) void attn_kernel(
    const u16* __restrict__ qb, const u16* __restrict__ kb,
    const u16* __restrict__ vb, const float* __restrict__ ALPHA,
    const float* __restrict__ BETA, const float* __restrict__ GAMMA,
    const float* __restrict__ DELTA, u16* __restrict__ obuf) {
  __shared__ u16 Ksh[224 * KSTR];
  __shared__ u16 Qsh[224 * KSTR];
  __shared__ u16 Vt[16 * VSTR];
  __shared__ u16 Pbuf[7][16 * KSTR];
  const int e = blockIdx.x, b = blockIdx.y;
  const size_t hb = (size_t)(b * NH + e);
  const int tid = threadIdx.x;
  const u32 ONE = 0x3F80u;

  if (tid < 224) {
    const int j = tid;
    const uint4* src = (const uint4*)(kb + (hb * W_ + j) * HD);
    uint4 a = src[0], b2 = src[1];
    *(uint4*)&Ksh[j * KSTR] = a;
    *(uint4*)&Ksh[j * KSTR + 8] = b2;
    float G = GAMMA[hb * 224 + j];
    float D = DELTA[hb * 224 + j];
    float jf = (float)j;
    float P = G * jf + D;
    u16 Phi = f2bf(P);
    float Plo = P - __uint_as_float((u32)Phi << 16);
    u32* ex = (u32*)&Ksh[j * KSTR + 16];
    ex[0] = (u32)f2bf(G) | ((u32)Phi << 16);
    ex[1] = (u32)f2bf(Plo) | ((u32)f2bf(jf) << 16);
    ex[2] = ONE | (ONE << 16);
#pragma unroll
    for (int z = 3; z < 12; ++z) ex[z] = 0;
    const uint4* vsrc = (const uint4*)(vb + (hb * W_ + j) * HD);
    uint4 va = vsrc[0], vb4 = vsrc[1];
    u32 w[8] = {va.x, va.y, va.z, va.w, vb4.x, vb4.y, vb4.z, vb4.w};
#pragma unroll
    for (int c = 0; c < 16; ++c)
      Vt[c * VSTR + j] = (c & 1) ? (u16)(w[c >> 1] >> 16) : (u16)(w[c >> 1] & 0xFFFF);
  } else {
    const int i = tid - 224;
    const uint4* src = (const uint4*)(qb + (hb * W_ + i) * HD);
    uint4 a = src[0], b2 = src[1];
    *(uint4*)&Qsh[i * KSTR] = a;
    *(uint4*)&Qsh[i * KSTR + 8] = b2;
    float al = ALPHA[hb * 224 + i];
    float be = BETA[hb * 224 + i];
    float ifl = (float)i;
    float Q = be - al * ifl;
    u16 Qhi = f2bf(Q);
    float Qlo = Q - __uint_as_float((u32)Qhi << 16);
    u32* ex = (u32*)&Qsh[i * KSTR + 16];
    ex[0] = (u32)f2bf(-ifl) | (ONE << 16);
    ex[1] = ONE | ((u32)f2bf(al) << 16);
    ex[2] = (u32)Qhi | ((u32)f2bf(Qlo) << 16);
#pragma unroll
    for (int z = 3; z < 12; ++z) ex[z] = 0;
  }
  __syncthreads();

  const int wid = tid >> 6, lane = tid & 63;
  const int g = lane >> 4, li = lane & 15;
  u16* pb = &Pbuf[wid][0];
  const int obase = (b & 128) ? ROWS_ : 0;
  const int blow = b & 127;

  for (int qt = wid * 2; qt < wid * 2 + 2; ++qt) {
    const int i0 = qt * 16;
    const bf16x8 Bq = *(const bf16x8*)&Qsh[(i0 + li) * KSTR + g * 8];
    f32x4 C[7][2];
#pragma unroll
    for (int js = 0; js < 7; ++js) {
      const bf16x8 A0 = *(const bf16x8*)&Ksh[(js * 32 + li) * KSTR + g * 8];
      const bf16x8 A1 = *(const bf16x8*)&Ksh[(js * 32 + 16 + li) * KSTR + g * 8];
      const f32x4 Z = {0.f, 0.f, 0.f, 0.f};
      C[js][0] = __builtin_amdgcn_mfma_f32_16x16x32_bf16(A0, Bq, Z, 0, 0, 0);
      C[js][1] = __builtin_amdgcn_mfma_f32_16x16x32_bf16(A1, Bq, Z, 0, 0, 0);
    }
    float m = -1e30f;
#pragma unroll
    for (int js = 0; js < 7; ++js)
#pragma unroll
      for (int h = 0; h < 2; ++h)
        m = fmaxf(m, fmaxf(fmaxf(C[js][h][0], C[js][h][1]), fmaxf(C[js][h][2], C[js][h][3])));
    m = fmaxf(m, __shfl_xor(m, 16));
    m = fmaxf(m, __shfl_xor(m, 32));
    f32x4 O = {0.f, 0.f, 0.f, 0.f};
    float lsum = 0.f;
#pragma unroll
    for (int js = 0; js < 7; ++js) {
      float p0 = __expf(C[js][0][0] - m), p1 = __expf(C[js][0][1] - m);
      float p2 = __expf(C[js][0][2] - m), p3 = __expf(C[js][0][3] - m);
      float p4 = __expf(C[js][1][0] - m), p5 = __expf(C[js][1][1] - m);
      float p6 = __expf(C[js][1][2] - m), p7 = __expf(C[js][1][3] - m);
      lsum += ((p0 + p1) + (p2 + p3)) + ((p4 + p5) + (p6 + p7));
      u16* pr = pb + li * KSTR + g * 4;
      pr[0] = f2bf(p0); pr[1] = f2bf(p1); pr[2] = f2bf(p2); pr[3] = f2bf(p3);
      pr[16] = f2bf(p4); pr[17] = f2bf(p5); pr[18] = f2bf(p6); pr[19] = f2bf(p7);
      const bf16x8 Ap = *(const bf16x8*)&Pbuf[wid][li * KSTR + g * 8];
      const bf16x8 Bv = *(const bf16x8*)&Vt[li * VSTR + js * 32 + g * 8];
      O = __builtin_amdgcn_mfma_f32_16x16x32_bf16(Ap, Bv, O, 0, 0, 0);
    }
    lsum += __shfl_xor(lsum, 16);
    lsum += __shfl_xor(lsum, 32);
#pragma unroll
    for (int r = 0; r < 4; ++r) {
      const float lr = __shfl(lsum, g * 4 + r);
      const int irow = i0 + g * 4 + r;
      obuf[((size_t)(obase + irow * 128 + blow)) * C_ + e * HD + li] = f2bf(O[r] * (1.f / lr));
    }
  }
}

// Gather x_l/x_r[b][c][h][w] -> bf16 rows p = img*28672 + w*128 + h*2 + b.
__global__ __launch_bounds__(256) void transpose_kernel(const float* __restrict__ x_l,
                                                        const float* __restrict__ x_r,
                                                        u16* __restrict__ xT) {
  __shared__ float tile[128][57];
  const int wt = blockIdx.x * 56, hi = blockIdx.y;
  const int img = blockIdx.z >> 1, bi = blockIdx.z & 1;
  const float* x = img ? x_r : x_l;
  const int wave = threadIdx.x >> 6, lane = threadIdx.x & 63;
  for (int c = wave; c < 128; c += 4) {
    if (lane < 56)
      tile[c][lane] = x[(((size_t)bi * 128 + c) * 64 + hi) * 224 + wt + lane];
  }
  __syncthreads();
  u32* dst = (u32*)xT;
  for (int w = wave; w < 56; w += 4) {
    int p = img * ROWS_ + (wt + w) * 128 + hi * 2 + bi;
    float a = tile[lane * 2][w], b2 = tile[lane * 2 + 1][w];
    dst[(size_t)p * 64 + lane] = (u32)f2bf(a) | ((u32)f2bf(b2) << 16);
  }
}

// ---------------------------------------------------------------------------
// Final soft-argmax, MFMA version. Block = (b, i-half of 112). K rows (all 8
// heads = 128-dim) staged in LDS (stride 136); Q B-fragments loaded directly
// from global (per-lane 16B-aligned). 56 MFMAs/wave build the full 224-j
// logit strip in registers; exact max -> exp -> soft-argmax.
// ---------------------------------------------------------------------------
__global__ __launch_bounds__(448) void corresp_kernel(
    const u16* __restrict__ qb, const u16* __restrict__ kb,
    const float* __restrict__ ALPHA, const float* __restrict__ BETA,
    const float* __restrict__ GAMMA, const float* __restrict__ DELTA,
    float* __restrict__ out) {
  __shared__ u16 Ksh[224 * 136];   // 60,928 B
  __shared__ float Gs[224], Ds[224];
  const int b = blockIdx.x, tid = threadIdx.x;
  if (tid < 224) {
    const int j = tid;
#pragma unroll
    for (int e = 0; e < 8; ++e) {
      const uint4* src = (const uint4*)(kb + ((size_t)(b * 8 + e) * 224 + j) * 16);
      *(uint4*)&Ksh[j * 136 + e * 16] = src[0];
      *(uint4*)&Ksh[j * 136 + e * 16 + 8] = src[1];
    }
    float gs = 0.f, ds = 0.f;
#pragma unroll
    for (int e = 0; e < 8; ++e) {
      gs += GAMMA[((size_t)(b * 8 + e)) * 224 + j];
      ds += DELTA[((size_t)(b * 8 + e)) * 224 + j];
    }
    Gs[j] = gs;
    Ds[j] = ds;
  }
  __syncthreads();
  const int wid = tid >> 6, lane = tid & 63;
  const int g = lane >> 4, li = lane & 15;
  const int i = blockIdx.y * 112 + wid * 16 + li;
  // Q B-operand fragments straight from global: k-dim = e*16+c over 8 heads
  bf16x8 Bq[4];
#pragma unroll
  for (int ks = 0; ks < 4; ++ks) {
    const int e2 = ks * 2 + (g >> 1), c0 = (g & 1) * 8;
    Bq[ks] = *(const bf16x8*)&qb[((size_t)(b * 8 + e2) * 224 + i) * 16 + c0];
  }
  f32x4 C[14];
#pragma unroll
  for (int js = 0; js < 14; ++js) {
    f32x4 acc = {0.f, 0.f, 0.f, 0.f};
#pragma unroll
    for (int ks = 0; ks < 4; ++ks) {
      const bf16x8 A = *(const bf16x8*)&Ksh[(js * 16 + li) * 136 + ks * 32 + g * 8];
      acc = __builtin_amdgcn_mfma_f32_16x16x32_bf16(A, Bq[ks], acc, 0, 0, 0);
    }
    C[js] = acc;
  }
  float ai = 0.f, bi_ = 0.f;
#pragma unroll
  for (int e = 0; e < 8; ++e) {
    ai += ALPHA[((size_t)(b * 8 + e)) * 224 + i];
    bi_ += BETA[((size_t)(b * 8 + e)) * 224 + i];
  }
  const float ifl = (float)i;
  float m = -1e30f;
#pragma unroll
  for (int js = 0; js < 14; ++js) {
#pragma unroll
    for (int r = 0; r < 4; ++r) {
      const int j = js * 16 + g * 4 + r;
      float s = C[js][r] + ((float)j - ifl) * (ai + Gs[j]) + bi_ + Ds[j];
      C[js][r] = s;
      m = fmaxf(m, s);
    }
  }
  m = fmaxf(m, __shfl_xor(m, 16));
  m = fmaxf(m, __shfl_xor(m, 32));
  float l = 0.f, wj = 0.f;
#pragma unroll
  for (int js = 0; js < 14; ++js) {
#pragma unroll
    for (int r = 0; r < 4; ++r) {
      const float p = __expf(C[js][r] - m);
      l += p;
      wj += p * (float)(js * 16 + g * 4 + r);
    }
  }
  l += __shfl_xor(l, 16);
  l += __shfl_xor(l, 32);
  wj += __shfl_xor(wj, 16);
  wj += __shfl_xor(wj, 32);
  if (g == 0) out[(size_t)b * 224 + i] = ifl - wj / fmaxf(l, 1e-30f);
}

// Single-launch conversion of all five weight tensors to one bf16 buffer.
#define OFF_FEAT 0
#define OFF_SWI 16384
#define OFF_SWO 311296
#define OFF_CWI 409600
#define OFF_CWO 704512
#define N_WALL 802816
__global__ __launch_bounds__(256) void cvt_all_kernel(
    const float* __restrict__ feat_w, const float* __restrict__ self_Wi,
    const float* __restrict__ self_Wo, const float* __restrict__ cross_Wi,
    const float* __restrict__ cross_Wo, u16* __restrict__ dst) {
  int idx = blockIdx.x * 256 + threadIdx.x;
  if (idx >= N_WALL) return;
  float v;
  if (idx < OFF_SWI)       v = feat_w[idx];
  else if (idx < OFF_SWO)  v = self_Wi[idx - OFF_SWI];
  else if (idx < OFF_CWI)  v = self_Wo[idx - OFF_SWO];
  else if (idx < OFF_CWO)  v = cross_Wi[idx - OFF_CWI];
  else                     v = cross_Wo[idx - OFF_CWO];
  dst[idx] = f2bf(v);
}

extern "C" void kernel_launch(void* const* d_in, const int* in_sizes, int n_in,
                              void* d_out, int out_size, void* d_ws, size_t ws_size,
                              hipStream_t stream) {
  (void)in_sizes; (void)n_in; (void)out_size; (void)ws_size;
  const float* x_l = (const float*)d_in[0];
  const float* x_r = (const float*)d_in[1];
  const float* feat_w = (const float*)d_in[2];
  const float* feat_b = (const float*)d_in[3];
  const float* self_Wi = (const float*)d_in[4];
  const float* self_bi = (const float*)d_in[5];
  const float* self_Wo = (const float*)d_in[6];
  const float* self_bo = (const float*)d_in[7];
  const float* cross_Wi = (const float*)d_in[8];
  const float* cross_bi = (const float*)d_in[9];
  const float* cross_Wo = (const float*)d_in[10];
  const float* cross_bo = (const float*)d_in[11];
  const float* ln_g = (const float*)d_in[12];
  const float* ln_b = (const float*)d_in[13];

  char* ws = (char*)d_ws;
  size_t off = 0;
  auto alloc = [&](size_t bytes) {
    char* p = ws + off;
    off += (bytes + 255) & ~(size_t)255;
    return p;
  };
  // Total ~97 MB — under the R6-proven ~112 MB budget (R7/R8 lesson).
  float* XA = (float*)alloc((size_t)2 * ROWS_ * C_ * 4);   // residual (in-place LN)
  u16* QB = (u16*)alloc((size_t)256 * NH * W_ * HD * 2);   // also XT scratch
  u16* KB = (u16*)alloc((size_t)256 * NH * W_ * HD * 2);
  u16* VB = (u16*)alloc((size_t)256 * NH * W_ * HD * 2);
  u16* OB = (u16*)alloc((size_t)2 * ROWS_ * C_ * 2);
  u16* WALL = (u16*)alloc((size_t)N_WALL * 2);
  float* PREP = (float*)alloc((size_t)12 * PREP_STRIDE * 4);
  float* ALPHA = (float*)alloc((size_t)256 * NH * W_ * 4);
  float* BETA = (float*)alloc((size_t)256 * NH * W_ * 4);
  float* GAMMA = (float*)alloc((size_t)256 * NH * W_ * 4);
  float* DELTA = (float*)alloc((size_t)256 * NH * W_ * 4);

  cvt_all_kernel<<<3136, 256, 0, stream>>>(feat_w, self_Wi, self_Wo, cross_Wi, cross_Wo, WALL);
  prep_kernel<<<12, 256, 0, stream>>>(self_Wi, self_bi, cross_Wi, cross_bi, PREP);

  transpose_kernel<<<dim3(4, 64, 4), 256, 0, stream>>>(x_l, x_r, QB);
  gemm_plain<<<dim3(896, 2), 256, 0, stream>>>(QB, WALL + OFF_FEAT, feat_b, 5, XA);

  for (int l = 0; l < 6; ++l) {
    const u16* sWi = WALL + OFF_SWI + (size_t)l * 384 * 128;
    const u16* sWo = WALL + OFF_SWO + (size_t)l * 128 * 128;
    const u16* cWi = WALL + OFF_CWI + (size_t)l * 384 * 128;
    const u16* cWo = WALL + OFF_CWO + (size_t)l * 128 * 128;
    const float* sbi = self_bi + l * 384;
    const float* sbo = self_bo + l * 128;
    const float* cbi = cross_bi + l * 384;
    const float* cbo = cross_bo + l * 128;
    const float* ps = PREP + (size_t)(l * 2) * PREP_STRIDE;
    const float* pc = PREP + (size_t)(l * 2 + 1) * PREP_STRIDE;

    // --- self attention on xl AND xr: X = LN(X) (+tables), qkv, attn, +=proj ---
    tab_kernel<<<1792, 256, 0, stream>>>(XA, ln_g, ln_b, ps, ps + 4096, ALPHA, BETA,
                                         ps + 2048, ps + 4112, GAMMA, DELTA, 0);
    gemm_qkv_self<<<dim3(896, 3), 256, 0, stream>>>(XA, sWi, sbi, QB, KB, VB);
    attn_kernel<<<dim3(8, 256), 448, 0, stream>>>(QB, KB, VB, ALPHA, BETA, GAMMA, DELTA, OB);
    gemm_plain<<<dim3(896, 2), 256, 0, stream>>>(OB, sWo, sbo, 4, XA);

    // --- cross attention: q from xr, k/v from xl; X = LN(X) first ---
    tab_kernel<<<1792, 256, 0, stream>>>(XA, ln_g, ln_b, pc, pc + 4096, ALPHA, BETA,
                                         pc + 2048, pc + 4112, GAMMA, DELTA, 1);
    gemm_qkv_cross<<<dim3(448, 3), 256, 0, stream>>>(XA, XA + (size_t)ROWS_ * C_, cWi, cbi,
                                                     QB, KB, VB);
    if (l < 5) {
      attn_kernel<<<dim3(8, 128), 448, 0, stream>>>(QB, KB, VB, ALPHA, BETA, GAMMA, DELTA, OB);
      gemm_plain<<<dim3(448, 2), 256, 0, stream>>>(OB, cWo, cbo, 4, XA);  // xl half only
    }
    // l == 5: attention output / x updates dead; corresp reads QB/KB + tables.
  }
  corresp_kernel<<<dim3(128, 2), 448, 0, stream>>>(QB, KB, ALPHA, BETA, GAMMA, DELTA,
                                                   (float*)d_out);
}